// Round 5
// baseline (289.196 us; speedup 1.0000x reference)
//
#include <hip/hip_runtime.h>

#define NEG_SLOPE 0.01f

using short8 = __attribute__((ext_vector_type(8))) short;
using f32x4  = __attribute__((ext_vector_type(4))) float;

__device__ inline float b2f(ushort u) {
    union { unsigned u; float f; } x; x.u = ((unsigned)u) << 16; return x.f;
}
__device__ inline ushort f2b(float f) {
    union { float f; unsigned u; } x; x.f = f;
    unsigned r = x.u + 0x7FFFu + ((x.u >> 16) & 1u);  // RNE
    return (ushort)(r >> 16);
}
__device__ inline void gload16(const void* g, void* l) {
    __builtin_amdgcn_global_load_lds((__attribute__((address_space(1))) void*)g,
                                     (__attribute__((address_space(3))) void*)l, 16, 0, 0);
}

// ---------------- CSR build ----------------

__global__ void count_pick(const int* __restrict__ dst, int* __restrict__ cnt, int E,
                           const int* __restrict__ batch, int* __restrict__ picked, int N) {
    int i = blockIdx.x * blockDim.x + threadIdx.x;
    if (i < E) atomicAdd(&cnt[dst[i]], 1);
    if (i < N) {
        if (i == 0 || batch[i] != batch[i - 1]) picked[batch[i]] = i;
    }
}

__global__ __launch_bounds__(256) void scan_phase1(const int* __restrict__ cnt,
                                                   int* __restrict__ blockSums,
                                                   float* __restrict__ dis, int N) {
    __shared__ int lds[256];
    int b = blockIdx.x, t = threadIdx.x;
    int base = b * 1024 + t * 4;
    int v[4] = {0, 0, 0, 0};
    if (base + 3 < N) {
        int4 q = *(const int4*)(cnt + base);
        v[0] = q.x; v[1] = q.y; v[2] = q.z; v[3] = q.w;
    } else {
        for (int i = 0; i < 4; i++) if (base + i < N) v[i] = cnt[base + i];
    }
#pragma unroll
    for (int i = 0; i < 4; i++)
        if (base + i < N) dis[base + i] = rsqrtf((float)v[i] + 1.0f);
    lds[t] = v[0] + v[1] + v[2] + v[3];
    __syncthreads();
    for (int off = 128; off > 0; off >>= 1) {
        if (t < off) lds[t] += lds[t + off];
        __syncthreads();
    }
    if (t == 0) blockSums[b] = lds[0];
}

__global__ __launch_bounds__(1024) void scan_phase2(int* __restrict__ blockSums, int nb) {
    __shared__ int lds[1024];
    int t = threadIdx.x;
    int v = (t < nb) ? blockSums[t] : 0;
    lds[t] = v;
    __syncthreads();
    for (int off = 1; off < 1024; off <<= 1) {
        int u = (t >= off) ? lds[t - off] : 0;
        __syncthreads();
        lds[t] += u;
        __syncthreads();
    }
    if (t < nb) blockSums[t] = lds[t] - v;  // exclusive
}

__global__ __launch_bounds__(256) void scan_phase3(const int* __restrict__ cnt,
                                                   const int* __restrict__ blockSums,
                                                   int* __restrict__ rowptr,
                                                   int* __restrict__ cur, int N, int E) {
    __shared__ int lds[256];
    int b = blockIdx.x, t = threadIdx.x;
    int base = b * 1024 + t * 4;
    int v[4] = {0, 0, 0, 0};
    if (base + 3 < N) {
        int4 q = *(const int4*)(cnt + base);
        v[0] = q.x; v[1] = q.y; v[2] = q.z; v[3] = q.w;
    } else {
        for (int i = 0; i < 4; i++) if (base + i < N) v[i] = cnt[base + i];
    }
    int s = v[0] + v[1] + v[2] + v[3];
    lds[t] = s;
    __syncthreads();
    for (int off = 1; off < 256; off <<= 1) {
        int u = (t >= off) ? lds[t - off] : 0;
        __syncthreads();
        lds[t] += u;
        __syncthreads();
    }
    int run = blockSums[b] + lds[t] - s;
#pragma unroll
    for (int i = 0; i < 4; i++) {
        if (base + i < N) { rowptr[base + i] = run; cur[base + i] = run; }
        run += v[i];
    }
    if (b == 0 && t == 0) rowptr[N] = E;
}

__global__ void fill_kernel(const int* __restrict__ src, const int* __restrict__ dst,
                            int* __restrict__ cur, int* __restrict__ col, int E) {
    int e = blockIdx.x * blockDim.x + threadIdx.x;
    if (e < E) {
        int pos = atomicAdd(&cur[dst[e]], 1);
        col[pos] = src[e];
    }
}

// ---------------- fused prep: W1t, W2t (bf16 transposed), xs = bf16(dis*x) ----------------

__global__ void prep_kernel(const float* __restrict__ W1, ushort* __restrict__ W1t,
                            const float* __restrict__ W2, ushort* __restrict__ W2t,
                            const float* __restrict__ x, const float* __restrict__ dis,
                            ushort* __restrict__ xs, int n4) {  // n4 = N*128/4
    int idx = blockIdx.x * blockDim.x + threadIdx.x;
    if (idx < 32768) {                       // W1t[n][k] = W1[k][n], K=128
        int n = idx >> 7, k = idx & 127;
        W1t[idx] = f2b(W1[k * 256 + n]);
    } else if (idx < 98304) {                // W2t[n][k] = W2[k][n], K=256
        int j = idx - 32768;
        int n = j >> 8, k = j & 255;
        W2t[j] = f2b(W2[k * 256 + n]);
    } else {
        int j = idx - 98304;
        if (j < n4) {
            float4 v = ((const float4*)x)[j];
            float d = dis[j >> 5];           // 32 float4 per 128-wide row
            ushort4 o;
            o.x = f2b(v.x * d); o.y = f2b(v.y * d); o.z = f2b(v.z * d); o.w = f2b(v.w * d);
            ((ushort4*)xs)[j] = o;
        }
    }
}

// ---------------- aggregation (layer 2): out[i] = bf16( dis_i * (sum h[s] + h[i]) ) ----------------
// h rows pre-scaled by dis_s, bf16. LPR lanes per row, 8 bf16 (16 B) per lane.

template <int LPR>
__global__ __launch_bounds__(256) void agg_kernel(const ushort* __restrict__ h,
                                                  const float* __restrict__ dis,
                                                  const int* __restrict__ rowptr,
                                                  const int* __restrict__ col,
                                                  ushort* __restrict__ out, int N) {
    constexpr int W = LPR * 8;
    constexpr int GR = 64 / LPR;
    int wave = blockIdx.x * 4 + (threadIdx.x >> 6);
    int lane = threadIdx.x & 63;
    int node = wave * GR + lane / LPR;
    int li = lane & (LPR - 1);
    if (node >= N) return;

    const ushort* hp = h + (size_t)li * 8;
    float di = dis[node];
    float a[8];
    {
        short8 v = *(const short8*)(hp + (size_t)node * W);
#pragma unroll
        for (int j = 0; j < 8; j++) a[j] = b2f((ushort)v[j]);
    }
    int e = rowptr[node], e1 = rowptr[node + 1];
    for (; e + 4 <= e1; e += 4) {
        int s0 = col[e], s1 = col[e + 1], s2 = col[e + 2], s3 = col[e + 3];
        short8 v0 = *(const short8*)(hp + (size_t)s0 * W);
        short8 v1 = *(const short8*)(hp + (size_t)s1 * W);
        short8 v2 = *(const short8*)(hp + (size_t)s2 * W);
        short8 v3 = *(const short8*)(hp + (size_t)s3 * W);
#pragma unroll
        for (int j = 0; j < 8; j++)
            a[j] += (b2f((ushort)v0[j]) + b2f((ushort)v1[j])) +
                    (b2f((ushort)v2[j]) + b2f((ushort)v3[j]));
    }
    for (; e < e1; e++) {
        int s0 = col[e];
        short8 v0 = *(const short8*)(hp + (size_t)s0 * W);
#pragma unroll
        for (int j = 0; j < 8; j++) a[j] += b2f((ushort)v0[j]);
    }
    short8 o;
#pragma unroll
    for (int j = 0; j < 8; j++) o[j] = (short)f2b(di * a[j]);
    *(short8*)(out + (size_t)node * W + li * 8) = o;
}

// ---------------- fused layer 1: aggregate xs into LDS As, then As @ W1t^T -> h1p ----------------
// Block: 512 threads (8 waves), output tile 128 rows x 256 cols, K=128.
// As: [128 rows][16 chunks of 8 bf16], chunk c stored at c^(row&7) (swizzle write+read).
// Bs: [256 rows][8 chunks], staged per 64-k-tile via global_load_lds with pre-swizzled source.

__global__ __launch_bounds__(512) void gemm1_fused(const ushort* __restrict__ xs,
                                                   const float* __restrict__ dis,
                                                   const int* __restrict__ rowptr,
                                                   const int* __restrict__ col,
                                                   const ushort* __restrict__ W1t,
                                                   const float* __restrict__ bias,
                                                   ushort* __restrict__ C, int N) {
    constexpr int K = 128;
    __shared__ ushort As[128 * 128];  // 32 KB
    __shared__ ushort Bs[256 * 64];   // 32 KB
    const int t = threadIdx.x;
    const int lane = t & 63;
    const int w = t >> 6;
    const int row0 = blockIdx.x * 128;

    // ---- phase A: gather-aggregate 128 rows of width 128 into As ----
    // wave w: nodes row0 + w*16 + g*4 + (lane>>4), 16 lanes (16 B) per row
#pragma unroll
    for (int g = 0; g < 4; g++) {
        int r = w * 16 + g * 4 + (lane >> 4);
        int node = row0 + r;
        int li = lane & 15;
        float a[8] = {};
        if (node < N) {
            const ushort* hp = xs + (size_t)li * 8;
            short8 v = *(const short8*)(hp + (size_t)node * K);  // self (dis_i-scaled)
#pragma unroll
            for (int j = 0; j < 8; j++) a[j] = b2f((ushort)v[j]);
            int e = rowptr[node], e1 = rowptr[node + 1];
            for (; e + 2 <= e1; e += 2) {
                int s0 = col[e], s1 = col[e + 1];
                short8 v0 = *(const short8*)(hp + (size_t)s0 * K);
                short8 v1 = *(const short8*)(hp + (size_t)s1 * K);
#pragma unroll
                for (int j = 0; j < 8; j++) a[j] += b2f((ushort)v0[j]) + b2f((ushort)v1[j]);
            }
            if (e < e1) {
                short8 v0 = *(const short8*)(hp + (size_t)col[e] * K);
#pragma unroll
                for (int j = 0; j < 8; j++) a[j] += b2f((ushort)v0[j]);
            }
            float di = dis[node];
#pragma unroll
            for (int j = 0; j < 8; j++) a[j] *= di;
        }
        short8 o;
#pragma unroll
        for (int j = 0; j < 8; j++) o[j] = (short)f2b(a[j]);
        *(short8*)&As[r * 128 + ((li ^ (r & 7)) * 8)] = o;  // swizzled write
    }

    // ---- phase B: GEMM over K=128, 2 k-tiles of 64 ----
    const int wm = w >> 2, wn = w & 3;  // 2x4 wave grid -> 64x64 each
    f32x4 acc[4][4] = {};
#pragma unroll
    for (int kt = 0; kt < 2; kt++) {
        __syncthreads();  // As ready (kt=0) / previous Bs reads done (kt=1)
#pragma unroll
        for (int it = 0; it < 4; it++) {
            int q = it * 512 + t;          // 2048 chunks
            int r = q >> 3, c = q & 7;
            int cs = c ^ (r & 7);          // pre-swizzled source
            gload16(W1t + (size_t)r * K + kt * 64 + cs * 8, &Bs[q * 8]);
        }
        __syncthreads();
#pragma unroll
        for (int ks = 0; ks < 2; ks++) {
            short8 a[4], b[4];
            int ccA = kt * 8 + ks * 4 + (lane >> 4);  // chunk of 16 in As row
            int ccB = ks * 4 + (lane >> 4);           // chunk of 8 in Bs row
#pragma unroll
            for (int m = 0; m < 4; m++) {
                int R = wm * 64 + m * 16 + (lane & 15);
                a[m] = *(const short8*)&As[R * 128 + ((ccA ^ (R & 7)) * 8)];
            }
#pragma unroll
            for (int n = 0; n < 4; n++) {
                int R = wn * 64 + n * 16 + (lane & 15);
                b[n] = *(const short8*)&Bs[R * 64 + ((ccB ^ (R & 7)) * 8)];
            }
#pragma unroll
            for (int m = 0; m < 4; m++)
#pragma unroll
                for (int n = 0; n < 4; n++)
                    acc[m][n] = __builtin_amdgcn_mfma_f32_16x16x32_bf16(a[m], b[n], acc[m][n], 0, 0, 0);
        }
    }

    // epilogue: C/D layout col=lane&15, row=(lane>>4)*4+j
#pragma unroll
    for (int m = 0; m < 4; m++) {
#pragma unroll
        for (int j = 0; j < 4; j++) {
            int grow = row0 + wm * 64 + m * 16 + (lane >> 4) * 4 + j;
            if (grow >= N) continue;
            float dr = dis[grow];
#pragma unroll
            for (int n = 0; n < 4; n++) {
                int gcol = wn * 64 + n * 16 + (lane & 15);
                float v = acc[m][n][j] + bias[gcol];
                v = v > 0.f ? v : NEG_SLOPE * v;
                C[(size_t)grow * 256 + gcol] = f2b(v * dr);
            }
        }
    }
}

// ---------------- full-width MFMA GEMM (layer 2): C[M x 256] = f(A[M x 256] @ Bt^T) ----------------
// 512 threads, 8 waves (2x4), A read once. LDS XOR-swizzled via pre-swizzled gload source.

template <int K>
__global__ __launch_bounds__(512) void gemm_bf16w(const ushort* __restrict__ A,
                                                  const ushort* __restrict__ Bt,
                                                  const float* __restrict__ bias,
                                                  const float* __restrict__ dis,
                                                  ushort* __restrict__ C, int M) {
    __shared__ ushort As[128 * 64];   // 16 KB
    __shared__ ushort Bs[256 * 64];   // 32 KB
    const int t = threadIdx.x;
    const int lane = t & 63;
    const int w = t >> 6;
    const int wm = w >> 2, wn = w & 3;
    const int row0 = blockIdx.x * 128;

    f32x4 acc[4][4] = {};

    for (int kt = 0; kt < K / 64; kt++) {
#pragma unroll
        for (int it = 0; it < 2; it++) {           // As: 1024 chunks
            int q = it * 512 + t;
            int r = q >> 3, c = q & 7;
            int cs = c ^ (r & 7);
            int ga = min(row0 + r, M - 1);
            gload16(A + (size_t)ga * K + kt * 64 + cs * 8, &As[q * 8]);
        }
#pragma unroll
        for (int it = 0; it < 4; it++) {           // Bs: 2048 chunks
            int q = it * 512 + t;
            int r = q >> 3, c = q & 7;
            int cs = c ^ (r & 7);
            gload16(Bt + (size_t)r * K + kt * 64 + cs * 8, &Bs[q * 8]);
        }
        __syncthreads();
#pragma unroll
        for (int ks = 0; ks < 2; ks++) {
            short8 a[4], b[4];
            int cc = ks * 4 + (lane >> 4);
#pragma unroll
            for (int m = 0; m < 4; m++) {
                int R = wm * 64 + m * 16 + (lane & 15);
                a[m] = *(const short8*)&As[R * 64 + ((cc ^ (R & 7)) * 8)];
            }
#pragma unroll
            for (int n = 0; n < 4; n++) {
                int R = wn * 64 + n * 16 + (lane & 15);
                b[n] = *(const short8*)&Bs[R * 64 + ((cc ^ (R & 7)) * 8)];
            }
#pragma unroll
            for (int m = 0; m < 4; m++)
#pragma unroll
                for (int n = 0; n < 4; n++)
                    acc[m][n] = __builtin_amdgcn_mfma_f32_16x16x32_bf16(a[m], b[n], acc[m][n], 0, 0, 0);
        }
        __syncthreads();
    }

#pragma unroll
    for (int m = 0; m < 4; m++) {
#pragma unroll
        for (int j = 0; j < 4; j++) {
            int grow = row0 + wm * 64 + m * 16 + (lane >> 4) * 4 + j;
            if (grow >= M) continue;
            float dr = dis[grow];
#pragma unroll
            for (int n = 0; n < 4; n++) {
                int gcol = wn * 64 + n * 16 + (lane & 15);
                float v = acc[m][n][j] + bias[gcol];
                v = v > 0.f ? v : NEG_SLOPE * v;
                C[(size_t)grow * 256 + gcol] = f2b(v * dr);
            }
        }
    }
}

// ---------------- final: per graph, aggregate h2' at the root, then 256x16 GEMM ----------------

__global__ __launch_bounds__(256) void final_kernel(const ushort* __restrict__ h2,
                                                    const float* __restrict__ dis,
                                                    const int* __restrict__ rowptr,
                                                    const int* __restrict__ col,
                                                    const int* __restrict__ picked,
                                                    const float* __restrict__ W3,
                                                    const float* __restrict__ b3,
                                                    float* __restrict__ out, int G) {
    __shared__ float agg[256];
    __shared__ float red[256];
    int g = blockIdx.x;
    int t = threadIdx.x;
    if (g >= G) return;
    int i = picked[g];
    float di = dis[i];
    float a = b2f(h2[(size_t)i * 256 + t]);
    for (int e = rowptr[i]; e < rowptr[i + 1]; e++) {
        int s = col[e];
        a += b2f(h2[(size_t)s * 256 + t]);
    }
    agg[t] = di * a;
    __syncthreads();
    int c = t & 15, seg = t >> 4;
    float p = 0.f;
#pragma unroll
    for (int kk = 0; kk < 16; kk++) {
        int k = seg * 16 + kk;
        p += agg[k] * W3[k * 16 + c];
    }
    red[t] = p;
    __syncthreads();
    if (t < 16) {
        float sres = 0.f;
#pragma unroll
        for (int ss = 0; ss < 16; ss++) sres += red[ss * 16 + t];
        out[g * 16 + t] = sres + b3[t];
    }
}

// ---------------- launch ----------------

extern "C" void kernel_launch(void* const* d_in, const int* in_sizes, int n_in,
                              void* d_out, int out_size, void* d_ws, size_t ws_size,
                              hipStream_t stream) {
    const float* x   = (const float*)d_in[0];
    const int* ei    = (const int*)d_in[1];
    const int* batch = (const int*)d_in[2];
    const float* W1  = (const float*)d_in[3];
    const float* b1  = (const float*)d_in[4];
    const float* W2  = (const float*)d_in[5];
    const float* b2  = (const float*)d_in[6];
    const float* W3  = (const float*)d_in[7];
    const float* b3  = (const float*)d_in[8];

    const int IN = 128, H = 256, OUT = 16;
    int N = in_sizes[0] / IN;
    int E = in_sizes[1] / 2;
    int G = out_size / OUT;
    const int* srcp = ei;
    const int* dstp = ei + E;

    char* p = (char*)d_ws;
    auto carve = [&](size_t bytes) {
        char* q = p;
        p += (bytes + 255) & ~(size_t)255;
        return q;
    };
    float*  dis    = (float*)carve((size_t)N * 4);
    int*    cnt    = (int*)carve((size_t)N * 4);
    int*    rowptr = (int*)carve(((size_t)N + 1) * 4);
    int*    cur    = (int*)carve((size_t)N * 4);
    int*    bsums  = (int*)carve(1024 * 4);
    int*    picked = (int*)carve((size_t)G * 4);
    int*    col    = (int*)carve((size_t)E * 4);
    ushort* W1t    = (ushort*)carve((size_t)256 * 128 * 2);
    ushort* W2t    = (ushort*)carve((size_t)256 * 256 * 2);
    ushort* R12    = (ushort*)carve((size_t)N * H * 2);  // xs, later agg1
    ushort* R3     = (ushort*)carve((size_t)N * H * 2);  // h1', later h2'

    ushort* xs   = R12;                     // [N][128]
    ushort* agg1 = R12;                     // [N][256] (xs dead after gemm1_fused)
    ushort* h1p  = R3;                      // [N][256]
    ushort* h2p  = R3;                      // [N][256]

    int nb = (N + 1023) / 1024;
    int cpN = (E > N ? E : N);

    // CSR build
    hipMemsetAsync(cnt, 0, (size_t)N * 4, stream);
    count_pick<<<(cpN + 255) / 256, 256, 0, stream>>>(dstp, cnt, E, batch, picked, N);
    scan_phase1<<<nb, 256, 0, stream>>>(cnt, bsums, dis, N);
    scan_phase2<<<1, 1024, 0, stream>>>(bsums, nb);
    scan_phase3<<<nb, 256, 0, stream>>>(cnt, bsums, rowptr, cur, N, E);
    fill_kernel<<<(E + 255) / 256, 256, 0, stream>>>(srcp, dstp, cur, col, E);

    // weights + x prep
    prep_kernel<<<(98304 + N * 32 + 255) / 256, 256, 0, stream>>>(W1, W1t, W2, W2t, x, dis, xs, N * 32);

    // layer 1 (fused): h1' = dis * leaky( [dis*(sum xs)] @ W1 + b1 )
    gemm1_fused<<<(N + 127) / 128, 512, 0, stream>>>(xs, dis, rowptr, col, W1t, b1, h1p, N);

    // layer 2: agg1 = dis*(sum h1'); h2' = dis*leaky(agg1@W2 + b2)
    agg_kernel<32><<<(N + 7) / 8, 256, 0, stream>>>(h1p, dis, rowptr, col, agg1, N);
    gemm_bf16w<256><<<(N + 127) / 128, 512, 0, stream>>>(agg1, W2t, b2, dis, h2p, N);

    // layer 3 at picked roots only
    final_kernel<<<G, 256, 0, stream>>>(h2p, dis, rowptr, col, picked, W3, b3, (float*)d_out, G);
}

// Round 6
// 281.778 us; speedup vs baseline: 1.0263x; 1.0263x over previous
//
#include <hip/hip_runtime.h>

#define NEG_SLOPE 0.01f

using short8 = __attribute__((ext_vector_type(8))) short;
using f32x4  = __attribute__((ext_vector_type(4))) float;

__device__ inline float b2f(ushort u) {
    union { unsigned u; float f; } x; x.u = ((unsigned)u) << 16; return x.f;
}
__device__ inline ushort f2b(float f) {
    union { float f; unsigned u; } x; x.f = f;
    unsigned r = x.u + 0x7FFFu + ((x.u >> 16) & 1u);  // RNE
    return (ushort)(r >> 16);
}
__device__ inline void gload16(const void* g, void* l) {
    __builtin_amdgcn_global_load_lds((__attribute__((address_space(1))) void*)g,
                                     (__attribute__((address_space(3))) void*)l, 16, 0, 0);
}

// ---------------- CSR build ----------------

__global__ void count_pick(const int* __restrict__ dst, int* __restrict__ cnt, int E,
                           const int* __restrict__ batch, int* __restrict__ picked, int N) {
    int i = blockIdx.x * blockDim.x + threadIdx.x;
    if (i < E) atomicAdd(&cnt[dst[i]], 1);
    if (i < N) {
        if (i == 0 || batch[i] != batch[i - 1]) picked[batch[i]] = i;
    }
}

__global__ __launch_bounds__(256) void scan_phase1(const int* __restrict__ cnt,
                                                   int* __restrict__ blockSums,
                                                   float* __restrict__ dis, int N) {
    __shared__ int lds[256];
    int b = blockIdx.x, t = threadIdx.x;
    int base = b * 1024 + t * 4;
    int v[4] = {0, 0, 0, 0};
    if (base + 3 < N) {
        int4 q = *(const int4*)(cnt + base);
        v[0] = q.x; v[1] = q.y; v[2] = q.z; v[3] = q.w;
    } else {
        for (int i = 0; i < 4; i++) if (base + i < N) v[i] = cnt[base + i];
    }
#pragma unroll
    for (int i = 0; i < 4; i++)
        if (base + i < N) dis[base + i] = rsqrtf((float)v[i] + 1.0f);
    lds[t] = v[0] + v[1] + v[2] + v[3];
    __syncthreads();
    for (int off = 128; off > 0; off >>= 1) {
        if (t < off) lds[t] += lds[t + off];
        __syncthreads();
    }
    if (t == 0) blockSums[b] = lds[0];
}

__global__ __launch_bounds__(1024) void scan_phase2(int* __restrict__ blockSums, int nb) {
    __shared__ int lds[1024];
    int t = threadIdx.x;
    int v = (t < nb) ? blockSums[t] : 0;
    lds[t] = v;
    __syncthreads();
    for (int off = 1; off < 1024; off <<= 1) {
        int u = (t >= off) ? lds[t - off] : 0;
        __syncthreads();
        lds[t] += u;
        __syncthreads();
    }
    if (t < nb) blockSums[t] = lds[t] - v;  // exclusive
}

__global__ __launch_bounds__(256) void scan_phase3(const int* __restrict__ cnt,
                                                   const int* __restrict__ blockSums,
                                                   int* __restrict__ rowptr,
                                                   int* __restrict__ cur, int N, int E) {
    __shared__ int lds[256];
    int b = blockIdx.x, t = threadIdx.x;
    int base = b * 1024 + t * 4;
    int v[4] = {0, 0, 0, 0};
    if (base + 3 < N) {
        int4 q = *(const int4*)(cnt + base);
        v[0] = q.x; v[1] = q.y; v[2] = q.z; v[3] = q.w;
    } else {
        for (int i = 0; i < 4; i++) if (base + i < N) v[i] = cnt[base + i];
    }
    int s = v[0] + v[1] + v[2] + v[3];
    lds[t] = s;
    __syncthreads();
    for (int off = 1; off < 256; off <<= 1) {
        int u = (t >= off) ? lds[t - off] : 0;
        __syncthreads();
        lds[t] += u;
        __syncthreads();
    }
    int run = blockSums[b] + lds[t] - s;
#pragma unroll
    for (int i = 0; i < 4; i++) {
        if (base + i < N) { rowptr[base + i] = run; cur[base + i] = run; }
        run += v[i];
    }
    if (b == 0 && t == 0) rowptr[N] = E;
}

__global__ void fill_kernel(const int* __restrict__ src, const int* __restrict__ dst,
                            int* __restrict__ cur, int* __restrict__ col, int E) {
    int e = blockIdx.x * blockDim.x + threadIdx.x;
    if (e < E) {
        int pos = atomicAdd(&cur[dst[e]], 1);
        col[pos] = src[e];
    }
}

// ---------------- fused prep: W1t, W2t (bf16 transposed), xs = bf16(dis*x) ----------------

__global__ void prep_kernel(const float* __restrict__ W1, ushort* __restrict__ W1t,
                            const float* __restrict__ W2, ushort* __restrict__ W2t,
                            const float* __restrict__ x, const float* __restrict__ dis,
                            ushort* __restrict__ xs, int n4) {  // n4 = N*128/4
    int idx = blockIdx.x * blockDim.x + threadIdx.x;
    if (idx < 32768) {                       // W1t[n][k] = W1[k][n], K=128
        int n = idx >> 7, k = idx & 127;
        W1t[idx] = f2b(W1[k * 256 + n]);
    } else if (idx < 98304) {                // W2t[n][k] = W2[k][n], K=256
        int j = idx - 32768;
        int n = j >> 8, k = j & 255;
        W2t[j] = f2b(W2[k * 256 + n]);
    } else {
        int j = idx - 98304;
        if (j < n4) {
            float4 v = ((const float4*)x)[j];
            float d = dis[j >> 5];           // 32 float4 per 128-wide row
            ushort4 o;
            o.x = f2b(v.x * d); o.y = f2b(v.y * d); o.z = f2b(v.z * d); o.w = f2b(v.w * d);
            ((ushort4*)xs)[j] = o;
        }
    }
}

// ---------------- aggregation: out[i] = bf16( dis_i * (sum_{s in N(i)} h[s] + h[i]) ) ----------------
// h rows pre-scaled by dis_s, bf16. LPR lanes per row, 8 bf16 (16 B) per lane; width = LPR*8.
// Output stored non-temporally: downstream GEMM reads it streaming; keep L2 for gather reads.

template <int LPR>
__global__ __launch_bounds__(256) void agg_kernel(const ushort* __restrict__ h,
                                                  const float* __restrict__ dis,
                                                  const int* __restrict__ rowptr,
                                                  const int* __restrict__ col,
                                                  ushort* __restrict__ out, int N) {
    constexpr int W = LPR * 8;
    constexpr int GR = 64 / LPR;
    int wave = blockIdx.x * 4 + (threadIdx.x >> 6);
    int lane = threadIdx.x & 63;
    int node = wave * GR + lane / LPR;
    int li = lane & (LPR - 1);
    if (node >= N) return;

    const ushort* hp = h + (size_t)li * 8;
    float di = dis[node];
    float a[8];
    {
        short8 v = *(const short8*)(hp + (size_t)node * W);
#pragma unroll
        for (int j = 0; j < 8; j++) a[j] = b2f((ushort)v[j]);
    }
    int e = rowptr[node], e1 = rowptr[node + 1];
    for (; e + 4 <= e1; e += 4) {
        int s0 = col[e], s1 = col[e + 1], s2 = col[e + 2], s3 = col[e + 3];
        short8 v0 = *(const short8*)(hp + (size_t)s0 * W);
        short8 v1 = *(const short8*)(hp + (size_t)s1 * W);
        short8 v2 = *(const short8*)(hp + (size_t)s2 * W);
        short8 v3 = *(const short8*)(hp + (size_t)s3 * W);
#pragma unroll
        for (int j = 0; j < 8; j++)
            a[j] += (b2f((ushort)v0[j]) + b2f((ushort)v1[j])) +
                    (b2f((ushort)v2[j]) + b2f((ushort)v3[j]));
    }
    for (; e < e1; e++) {
        int s0 = col[e];
        short8 v0 = *(const short8*)(hp + (size_t)s0 * W);
#pragma unroll
        for (int j = 0; j < 8; j++) a[j] += b2f((ushort)v0[j]);
    }
    short8 o;
#pragma unroll
    for (int j = 0; j < 8; j++) o[j] = (short)f2b(di * a[j]);
    __builtin_nontemporal_store(o, (short8*)(out + (size_t)node * W + li * 8));
}

// ---------------- full-width MFMA GEMM: C[M x 256] = bf16( dis_row * leaky(A @ Bt^T + bias) ) ----------------
// 512 threads, 8 waves (2x4), output tile 128x256, A read once.
// LDS XOR-swizzled (T2, both-sides): pre-swizzled global source -> linear gload dest; swizzled read.

template <int K>
__global__ __launch_bounds__(512) void gemm_bf16w(const ushort* __restrict__ A,
                                                  const ushort* __restrict__ Bt,
                                                  const float* __restrict__ bias,
                                                  const float* __restrict__ dis,
                                                  ushort* __restrict__ C, int M) {
    __shared__ ushort As[128 * 64];   // 16 KB
    __shared__ ushort Bs[256 * 64];   // 32 KB
    const int t = threadIdx.x;
    const int lane = t & 63;
    const int w = t >> 6;
    const int wm = w >> 2, wn = w & 3;
    const int row0 = blockIdx.x * 128;

    f32x4 acc[4][4] = {};

    for (int kt = 0; kt < K / 64; kt++) {
#pragma unroll
        for (int it = 0; it < 2; it++) {           // As: 1024 chunks
            int q = it * 512 + t;
            int r = q >> 3, c = q & 7;
            int cs = c ^ (r & 7);
            int ga = min(row0 + r, M - 1);
            gload16(A + (size_t)ga * K + kt * 64 + cs * 8, &As[q * 8]);
        }
#pragma unroll
        for (int it = 0; it < 4; it++) {           // Bs: 2048 chunks
            int q = it * 512 + t;
            int r = q >> 3, c = q & 7;
            int cs = c ^ (r & 7);
            gload16(Bt + (size_t)r * K + kt * 64 + cs * 8, &Bs[q * 8]);
        }
        __syncthreads();
#pragma unroll
        for (int ks = 0; ks < 2; ks++) {
            short8 a[4], b[4];
            int cc = ks * 4 + (lane >> 4);
#pragma unroll
            for (int m = 0; m < 4; m++) {
                int R = wm * 64 + m * 16 + (lane & 15);
                a[m] = *(const short8*)&As[R * 64 + ((cc ^ (R & 7)) * 8)];
            }
#pragma unroll
            for (int n = 0; n < 4; n++) {
                int R = wn * 64 + n * 16 + (lane & 15);
                b[n] = *(const short8*)&Bs[R * 64 + ((cc ^ (R & 7)) * 8)];
            }
#pragma unroll
            for (int m = 0; m < 4; m++)
#pragma unroll
                for (int n = 0; n < 4; n++)
                    acc[m][n] = __builtin_amdgcn_mfma_f32_16x16x32_bf16(a[m], b[n], acc[m][n], 0, 0, 0);
        }
        __syncthreads();
    }

    // epilogue: C/D layout col=lane&15, row=(lane>>4)*4+j
#pragma unroll
    for (int m = 0; m < 4; m++) {
#pragma unroll
        for (int j = 0; j < 4; j++) {
            int grow = row0 + wm * 64 + m * 16 + (lane >> 4) * 4 + j;
            if (grow >= M) continue;
            float dr = dis[grow];
#pragma unroll
            for (int n = 0; n < 4; n++) {
                int gcol = wn * 64 + n * 16 + (lane & 15);
                float v = acc[m][n][j] + bias[gcol];
                v = v > 0.f ? v : NEG_SLOPE * v;
                C[(size_t)grow * 256 + gcol] = f2b(v * dr);
            }
        }
    }
}

// ---------------- final: per graph, aggregate h2' at the root, then 256x16 GEMM ----------------

__global__ __launch_bounds__(256) void final_kernel(const ushort* __restrict__ h2,
                                                    const float* __restrict__ dis,
                                                    const int* __restrict__ rowptr,
                                                    const int* __restrict__ col,
                                                    const int* __restrict__ picked,
                                                    const float* __restrict__ W3,
                                                    const float* __restrict__ b3,
                                                    float* __restrict__ out, int G) {
    __shared__ float agg[256];
    __shared__ float red[256];
    int g = blockIdx.x;
    int t = threadIdx.x;
    if (g >= G) return;
    int i = picked[g];
    float di = dis[i];
    float a = b2f(h2[(size_t)i * 256 + t]);
    for (int e = rowptr[i]; e < rowptr[i + 1]; e++) {
        int s = col[e];
        a += b2f(h2[(size_t)s * 256 + t]);
    }
    agg[t] = di * a;
    __syncthreads();
    int c = t & 15, seg = t >> 4;
    float p = 0.f;
#pragma unroll
    for (int kk = 0; kk < 16; kk++) {
        int k = seg * 16 + kk;
        p += agg[k] * W3[k * 16 + c];
    }
    red[t] = p;
    __syncthreads();
    if (t < 16) {
        float sres = 0.f;
#pragma unroll
        for (int ss = 0; ss < 16; ss++) sres += red[ss * 16 + t];
        out[g * 16 + t] = sres + b3[t];
    }
}

// ---------------- launch ----------------

extern "C" void kernel_launch(void* const* d_in, const int* in_sizes, int n_in,
                              void* d_out, int out_size, void* d_ws, size_t ws_size,
                              hipStream_t stream) {
    const float* x   = (const float*)d_in[0];
    const int* ei    = (const int*)d_in[1];
    const int* batch = (const int*)d_in[2];
    const float* W1  = (const float*)d_in[3];
    const float* b1  = (const float*)d_in[4];
    const float* W2  = (const float*)d_in[5];
    const float* b2  = (const float*)d_in[6];
    const float* W3  = (const float*)d_in[7];
    const float* b3  = (const float*)d_in[8];

    const int IN = 128, H = 256, OUT = 16;
    int N = in_sizes[0] / IN;
    int E = in_sizes[1] / 2;
    int G = out_size / OUT;
    const int* srcp = ei;
    const int* dstp = ei + E;

    char* p = (char*)d_ws;
    auto carve = [&](size_t bytes) {
        char* q = p;
        p += (bytes + 255) & ~(size_t)255;
        return q;
    };
    float*  dis    = (float*)carve((size_t)N * 4);
    int*    cnt    = (int*)carve((size_t)N * 4);
    int*    rowptr = (int*)carve(((size_t)N + 1) * 4);
    int*    cur    = (int*)carve((size_t)N * 4);
    int*    bsums  = (int*)carve(1024 * 4);
    int*    picked = (int*)carve((size_t)G * 4);
    int*    col    = (int*)carve((size_t)E * 4);
    ushort* W1t    = (ushort*)carve((size_t)256 * 128 * 2);
    ushort* W2t    = (ushort*)carve((size_t)256 * 256 * 2);
    ushort* R12    = (ushort*)carve((size_t)N * H * 2);  // xs+aggX, later agg1
    ushort* R3     = (ushort*)carve((size_t)N * H * 2);  // h1', later h2'

    ushort* xs   = R12;                     // [N][128]
    ushort* aggX = R12 + (size_t)N * 128;   // [N][128]
    ushort* agg1 = R12;                     // [N][256] (xs/aggX dead by then)
    ushort* h1p  = R3;                      // [N][256]
    ushort* h2p  = R3;                      // [N][256]

    int nb = (N + 1023) / 1024;
    int cpN = (E > N ? E : N);

    // CSR build
    hipMemsetAsync(cnt, 0, (size_t)N * 4, stream);
    count_pick<<<(cpN + 255) / 256, 256, 0, stream>>>(dstp, cnt, E, batch, picked, N);
    scan_phase1<<<nb, 256, 0, stream>>>(cnt, bsums, dis, N);
    scan_phase2<<<1, 1024, 0, stream>>>(bsums, nb);
    scan_phase3<<<nb, 256, 0, stream>>>(cnt, bsums, rowptr, cur, N, E);
    fill_kernel<<<(E + 255) / 256, 256, 0, stream>>>(srcp, dstp, cur, col, E);

    // weights + x prep
    prep_kernel<<<(98304 + N * 32 + 255) / 256, 256, 0, stream>>>(W1, W1t, W2, W2t, x, dis, xs, N * 32);

    // layer 1: aggX = dis*(sum xs); h1' = dis*leaky(aggX@W1 + b1)
    agg_kernel<16><<<(N + 15) / 16, 256, 0, stream>>>(xs, dis, rowptr, col, aggX, N);
    gemm_bf16w<128><<<(N + 127) / 128, 512, 0, stream>>>(aggX, W1t, b1, dis, h1p, N);

    // layer 2: agg1 = dis*(sum h1'); h2' = dis*leaky(agg1@W2 + b2)
    agg_kernel<32><<<(N + 7) / 8, 256, 0, stream>>>(h1p, dis, rowptr, col, agg1, N);
    gemm_bf16w<256><<<(N + 127) / 128, 512, 0, stream>>>(agg1, W2t, b2, dis, h2p, N);

    // layer 3 at picked roots only
    final_kernel<<<G, 256, 0, stream>>>(h2p, dis, rowptr, col, picked, W3, b3, (float*)d_out, G);
}

// Round 7
// 193.894 us; speedup vs baseline: 1.4915x; 1.4533x over previous
//
#include <hip/hip_runtime.h>

#define NEG_SLOPE 0.01f

using short8 = __attribute__((ext_vector_type(8))) short;
using f32x4  = __attribute__((ext_vector_type(4))) float;

__device__ inline float b2f(ushort u) {
    union { unsigned u; float f; } x; x.u = ((unsigned)u) << 16; return x.f;
}
__device__ inline ushort f2b(float f) {
    union { float f; unsigned u; } x; x.f = f;
    unsigned r = x.u + 0x7FFFu + ((x.u >> 16) & 1u);  // RNE
    return (ushort)(r >> 16);
}
__device__ inline void gload16(const void* g, void* l) {
    __builtin_amdgcn_global_load_lds((__attribute__((address_space(1))) void*)g,
                                     (__attribute__((address_space(3))) void*)l, 16, 0, 0);
}

// ---------------- CSR build ----------------

__global__ void count_pick(const int* __restrict__ dst, int* __restrict__ cnt, int E,
                           const int* __restrict__ batch, int* __restrict__ picked, int N) {
    int i = blockIdx.x * blockDim.x + threadIdx.x;
    if (i < E) atomicAdd(&cnt[dst[i]], 1);
    if (i < N) {
        if (i == 0 || batch[i] != batch[i - 1]) picked[batch[i]] = i;
    }
}

__global__ __launch_bounds__(256) void scan_phase1(const int* __restrict__ cnt,
                                                   int* __restrict__ blockSums,
                                                   float* __restrict__ dis, int N) {
    __shared__ int lds[256];
    int b = blockIdx.x, t = threadIdx.x;
    int base = b * 1024 + t * 4;
    int v[4] = {0, 0, 0, 0};
    if (base + 3 < N) {
        int4 q = *(const int4*)(cnt + base);
        v[0] = q.x; v[1] = q.y; v[2] = q.z; v[3] = q.w;
    } else {
        for (int i = 0; i < 4; i++) if (base + i < N) v[i] = cnt[base + i];
    }
#pragma unroll
    for (int i = 0; i < 4; i++)
        if (base + i < N) dis[base + i] = rsqrtf((float)v[i] + 1.0f);
    lds[t] = v[0] + v[1] + v[2] + v[3];
    __syncthreads();
    for (int off = 128; off > 0; off >>= 1) {
        if (t < off) lds[t] += lds[t + off];
        __syncthreads();
    }
    if (t == 0) blockSums[b] = lds[0];
}

__global__ __launch_bounds__(1024) void scan_phase2(int* __restrict__ blockSums, int nb) {
    __shared__ int lds[1024];
    int t = threadIdx.x;
    int v = (t < nb) ? blockSums[t] : 0;
    lds[t] = v;
    __syncthreads();
    for (int off = 1; off < 1024; off <<= 1) {
        int u = (t >= off) ? lds[t - off] : 0;
        __syncthreads();
        lds[t] += u;
        __syncthreads();
    }
    if (t < nb) blockSums[t] = lds[t] - v;  // exclusive
}

__global__ __launch_bounds__(256) void scan_phase3(const int* __restrict__ cnt,
                                                   const int* __restrict__ blockSums,
                                                   int* __restrict__ rowptr,
                                                   int* __restrict__ cur, int N, int E) {
    __shared__ int lds[256];
    int b = blockIdx.x, t = threadIdx.x;
    int base = b * 1024 + t * 4;
    int v[4] = {0, 0, 0, 0};
    if (base + 3 < N) {
        int4 q = *(const int4*)(cnt + base);
        v[0] = q.x; v[1] = q.y; v[2] = q.z; v[3] = q.w;
    } else {
        for (int i = 0; i < 4; i++) if (base + i < N) v[i] = cnt[base + i];
    }
    int s = v[0] + v[1] + v[2] + v[3];
    lds[t] = s;
    __syncthreads();
    for (int off = 1; off < 256; off <<= 1) {
        int u = (t >= off) ? lds[t - off] : 0;
        __syncthreads();
        lds[t] += u;
        __syncthreads();
    }
    int run = blockSums[b] + lds[t] - s;
#pragma unroll
    for (int i = 0; i < 4; i++) {
        if (base + i < N) { rowptr[base + i] = run; cur[base + i] = run; }
        run += v[i];
    }
    if (b == 0 && t == 0) rowptr[N] = E;
}

__global__ void fill_kernel(const int* __restrict__ src, const int* __restrict__ dst,
                            int* __restrict__ cur, int* __restrict__ col, int E) {
    int e = blockIdx.x * blockDim.x + threadIdx.x;
    if (e < E) {
        int pos = atomicAdd(&cur[dst[e]], 1);
        col[pos] = src[e];
    }
}

// ---------------- frontier marking ----------------
// S1 = roots U N(roots); S2 = S1 U N(S1).  flagX are int arrays (0/1).

__global__ void frontier1(const int* __restrict__ picked, const int* __restrict__ rowptr,
                          const int* __restrict__ col, int* __restrict__ flag1, int G) {
    int wid = (blockIdx.x * blockDim.x + threadIdx.x) >> 6;
    int lane = threadIdx.x & 63;
    if (wid >= G) return;
    int r = picked[wid];
    if (lane == 0) flag1[r] = 1;
    int e1 = rowptr[r + 1];
    for (int e = rowptr[r] + lane; e < e1; e += 64) flag1[col[e]] = 1;
}

__global__ void frontier2(const int* __restrict__ rowptr, const int* __restrict__ col,
                          const int* __restrict__ flag1, int* __restrict__ flag2, int N) {
    int i = blockIdx.x * blockDim.x + threadIdx.x;
    if (i >= N || !flag1[i]) return;
    flag2[i] = 1;
    int e1 = rowptr[i + 1];
    for (int e = rowptr[i]; e < e1; e++) flag2[col[e]] = 1;
}

// ---------------- dual compaction scan: (flag1, flag2) -> pos1/pos2, list1/list2, counts ----------------

__global__ __launch_bounds__(256) void cscan1(const int* __restrict__ f1, const int* __restrict__ f2,
                                              int2* __restrict__ bsums, int N) {
    __shared__ int l1[256], l2[256];
    int b = blockIdx.x, t = threadIdx.x;
    int base = b * 1024 + t * 4;
    int s1 = 0, s2 = 0;
    if (base + 3 < N) {
        int4 a = *(const int4*)(f1 + base); s1 = a.x + a.y + a.z + a.w;
        int4 c = *(const int4*)(f2 + base); s2 = c.x + c.y + c.z + c.w;
    } else {
        for (int i = 0; i < 4; i++) if (base + i < N) { s1 += f1[base + i]; s2 += f2[base + i]; }
    }
    l1[t] = s1; l2[t] = s2;
    __syncthreads();
    for (int off = 128; off > 0; off >>= 1) {
        if (t < off) { l1[t] += l1[t + off]; l2[t] += l2[t + off]; }
        __syncthreads();
    }
    if (t == 0) bsums[b] = make_int2(l1[0], l2[0]);
}

__global__ __launch_bounds__(1024) void cscan2(int2* __restrict__ bsums, int* __restrict__ counts, int nb) {
    __shared__ int l1[1024], l2[1024];
    int t = threadIdx.x;
    int v1 = 0, v2 = 0;
    if (t < nb) { int2 v = bsums[t]; v1 = v.x; v2 = v.y; }
    l1[t] = v1; l2[t] = v2;
    __syncthreads();
    for (int off = 1; off < 1024; off <<= 1) {
        int u1 = (t >= off) ? l1[t - off] : 0;
        int u2 = (t >= off) ? l2[t - off] : 0;
        __syncthreads();
        l1[t] += u1; l2[t] += u2;
        __syncthreads();
    }
    if (t < nb) bsums[t] = make_int2(l1[t] - v1, l2[t] - v2);  // exclusive
    if (t == 1023) { counts[0] = l1[1023]; counts[1] = l2[1023]; }  // totals M1, M2
}

__global__ __launch_bounds__(256) void cscan3(const int* __restrict__ f1, const int* __restrict__ f2,
                                              const int2* __restrict__ bsums,
                                              int* __restrict__ pos1, int* __restrict__ pos2,
                                              int* __restrict__ list1, int* __restrict__ list2, int N) {
    __shared__ int l1[256], l2[256];
    int b = blockIdx.x, t = threadIdx.x;
    int base = b * 1024 + t * 4;
    int v1[4] = {0, 0, 0, 0}, v2[4] = {0, 0, 0, 0};
    if (base + 3 < N) {
        int4 a = *(const int4*)(f1 + base); v1[0] = a.x; v1[1] = a.y; v1[2] = a.z; v1[3] = a.w;
        int4 c = *(const int4*)(f2 + base); v2[0] = c.x; v2[1] = c.y; v2[2] = c.z; v2[3] = c.w;
    } else {
        for (int i = 0; i < 4; i++) if (base + i < N) { v1[i] = f1[base + i]; v2[i] = f2[base + i]; }
    }
    int s1 = v1[0] + v1[1] + v1[2] + v1[3];
    int s2 = v2[0] + v2[1] + v2[2] + v2[3];
    l1[t] = s1; l2[t] = s2;
    __syncthreads();
    for (int off = 1; off < 256; off <<= 1) {
        int u1 = (t >= off) ? l1[t - off] : 0;
        int u2 = (t >= off) ? l2[t - off] : 0;
        __syncthreads();
        l1[t] += u1; l2[t] += u2;
        __syncthreads();
    }
    int2 bs = bsums[b];
    int run1 = bs.x + l1[t] - s1;
    int run2 = bs.y + l2[t] - s2;
#pragma unroll
    for (int i = 0; i < 4; i++) {
        if (base + i < N) {
            if (v1[i]) { pos1[base + i] = run1; list1[run1] = base + i; }
            if (v2[i]) { pos2[base + i] = run2; list2[run2] = base + i; }
        }
        run1 += v1[i];
        run2 += v2[i];
    }
}

// ---------------- weight transposes (bf16) ----------------

__global__ void wtrans2(const float* __restrict__ W1, ushort* __restrict__ W1t,
                        const float* __restrict__ W2, ushort* __restrict__ W2t) {
    int idx = blockIdx.x * blockDim.x + threadIdx.x;
    if (idx < 32768) {                       // W1t[n][k] = W1[k][n], K=128
        int n = idx >> 7, k = idx & 127;
        W1t[idx] = f2b(W1[k * 256 + n]);
    } else if (idx < 98304) {                // W2t[n][k] = W2[k][n], K=256
        int j = idx - 32768;
        int n = j >> 8, k = j & 255;
        W2t[j] = f2b(W2[k * 256 + n]);
    }
}

// ---------------- layer-1 aggregation on S2 (compact): from f32 x directly ----------------
// aggXc[p][0..127] = bf16( dis_i * ( dis_i*x[i] + sum_{s in N(i)} dis_s*x[s] ) ), i = list2[p]

__global__ __launch_bounds__(256) void aggx_c(const float* __restrict__ x,
                                              const float* __restrict__ dis,
                                              const int* __restrict__ rowptr,
                                              const int* __restrict__ col,
                                              const int* __restrict__ list2,
                                              const int* __restrict__ counts,
                                              ushort* __restrict__ aggXc) {
    const int M2 = counts[1];
    int wave = blockIdx.x * 4 + (threadIdx.x >> 6);
    int lane = threadIdx.x & 63;
    int li = lane & 31, sub = lane >> 5;
    int stride = gridDim.x * 8;  // rows per sweep (2 rows/wave)
    const float* xp = x + li * 4;
    for (int p = wave * 2 + sub; p < M2; p += stride) {
        int node = list2[p];
        float di = dis[node];
        float4 sv = *(const float4*)(xp + (size_t)node * 128);
        float a0 = di * sv.x, a1 = di * sv.y, a2 = di * sv.z, a3 = di * sv.w;
        int e1 = rowptr[node + 1];
        for (int e = rowptr[node]; e < e1; e++) {
            int s = col[e];
            float w = dis[s];
            float4 v = *(const float4*)(xp + (size_t)s * 128);
            a0 += w * v.x; a1 += w * v.y; a2 += w * v.z; a3 += w * v.w;
        }
        ushort4 o;
        o.x = f2b(di * a0); o.y = f2b(di * a1); o.z = f2b(di * a2); o.w = f2b(di * a3);
        *(ushort4*)(aggXc + (size_t)p * 128 + li * 4) = o;
    }
}

// ---------------- layer-2 aggregation on S1 (compact), h1c indexed via pos2 ----------------
// agg1c[p][0..255] = bf16( dis_i * ( h1c[pos2[i]] + sum_s h1c[pos2[s]] ) ), i = list1[p]

__global__ __launch_bounds__(256) void agg2_c(const ushort* __restrict__ h1c,
                                              const float* __restrict__ dis,
                                              const int* __restrict__ rowptr,
                                              const int* __restrict__ col,
                                              const int* __restrict__ list1,
                                              const int* __restrict__ pos2,
                                              const int* __restrict__ counts,
                                              ushort* __restrict__ agg1c) {
    const int M1 = counts[0];
    int wave = blockIdx.x * 4 + (threadIdx.x >> 6);
    int lane = threadIdx.x & 63;
    int li = lane & 31, sub = lane >> 5;
    int stride = gridDim.x * 8;
    const ushort* hp = h1c + (size_t)li * 8;
    for (int p = wave * 2 + sub; p < M1; p += stride) {
        int i = list1[p];
        float di = dis[i];
        float a[8];
        {
            short8 v = *(const short8*)(hp + (size_t)pos2[i] * 256);
#pragma unroll
            for (int j = 0; j < 8; j++) a[j] = b2f((ushort)v[j]);
        }
        int e1 = rowptr[i + 1];
        for (int e = rowptr[i]; e < e1; e++) {
            short8 v = *(const short8*)(hp + (size_t)pos2[col[e]] * 256);
#pragma unroll
            for (int j = 0; j < 8; j++) a[j] += b2f((ushort)v[j]);
        }
        short8 o;
#pragma unroll
        for (int j = 0; j < 8; j++) o[j] = (short)f2b(di * a[j]);
        *(short8*)(agg1c + (size_t)p * 256 + li * 8) = o;
    }
}

// ---------------- compact MFMA GEMM: C[M x 256] = bf16( dis[list[row]] * leaky(A @ Bt^T + bias) ) ----------------
// 512 threads, 8 waves (2x4), tile 128x256, grid-stride over tiles; M read from counts[which].
// LDS XOR-swizzled (T2, both sides): pre-swizzled global source -> linear gload dest; swizzled read.

template <int K>
__global__ __launch_bounds__(512) void gemm_c(const ushort* __restrict__ A,
                                              const ushort* __restrict__ Bt,
                                              const float* __restrict__ bias,
                                              const float* __restrict__ dis,
                                              const int* __restrict__ list,
                                              const int* __restrict__ counts, int which,
                                              ushort* __restrict__ C) {
    __shared__ ushort As[128 * 64];   // 16 KB
    __shared__ ushort Bs[256 * 64];   // 32 KB
    const int M = counts[which];
    const int t = threadIdx.x;
    const int lane = t & 63;
    const int w = t >> 6;
    const int wm = w >> 2, wn = w & 3;

    for (int tile = blockIdx.x; tile * 128 < M; tile += gridDim.x) {
        const int row0 = tile * 128;
        f32x4 acc[4][4] = {};

        for (int kt = 0; kt < K / 64; kt++) {
#pragma unroll
            for (int it = 0; it < 2; it++) {           // As: 1024 chunks
                int q = it * 512 + t;
                int r = q >> 3, c = q & 7;
                int cs = c ^ (r & 7);
                int ga = min(row0 + r, M - 1);
                gload16(A + (size_t)ga * K + kt * 64 + cs * 8, &As[q * 8]);
            }
#pragma unroll
            for (int it = 0; it < 4; it++) {           // Bs: 2048 chunks
                int q = it * 512 + t;
                int r = q >> 3, c = q & 7;
                int cs = c ^ (r & 7);
                gload16(Bt + (size_t)r * K + kt * 64 + cs * 8, &Bs[q * 8]);
            }
            __syncthreads();
#pragma unroll
            for (int ks = 0; ks < 2; ks++) {
                short8 a[4], b[4];
                int cc = ks * 4 + (lane >> 4);
#pragma unroll
                for (int m = 0; m < 4; m++) {
                    int R = wm * 64 + m * 16 + (lane & 15);
                    a[m] = *(const short8*)&As[R * 64 + ((cc ^ (R & 7)) * 8)];
                }
#pragma unroll
                for (int n = 0; n < 4; n++) {
                    int R = wn * 64 + n * 16 + (lane & 15);
                    b[n] = *(const short8*)&Bs[R * 64 + ((cc ^ (R & 7)) * 8)];
                }
#pragma unroll
                for (int m = 0; m < 4; m++)
#pragma unroll
                    for (int n = 0; n < 4; n++)
                        acc[m][n] = __builtin_amdgcn_mfma_f32_16x16x32_bf16(a[m], b[n], acc[m][n], 0, 0, 0);
            }
            __syncthreads();
        }

        // epilogue: C/D layout col=lane&15, row=(lane>>4)*4+j
#pragma unroll
        for (int m = 0; m < 4; m++) {
#pragma unroll
            for (int j = 0; j < 4; j++) {
                int grow = row0 + wm * 64 + m * 16 + (lane >> 4) * 4 + j;
                if (grow >= M) continue;
                float dr = dis[list[grow]];
#pragma unroll
                for (int n = 0; n < 4; n++) {
                    int gcol = wn * 64 + n * 16 + (lane & 15);
                    float v = acc[m][n][j] + bias[gcol];
                    v = v > 0.f ? v : NEG_SLOPE * v;
                    C[(size_t)grow * 256 + gcol] = f2b(v * dr);
                }
            }
        }
    }
}

// ---------------- final: per graph, aggregate h2c at the root (via pos1), then 256x16 GEMM ----------------

__global__ __launch_bounds__(256) void final_c(const ushort* __restrict__ h2c,
                                               const float* __restrict__ dis,
                                               const int* __restrict__ rowptr,
                                               const int* __restrict__ col,
                                               const int* __restrict__ picked,
                                               const int* __restrict__ pos1,
                                               const float* __restrict__ W3,
                                               const float* __restrict__ b3,
                                               float* __restrict__ out, int G) {
    __shared__ float agg[256];
    __shared__ float red[256];
    int g = blockIdx.x;
    int t = threadIdx.x;
    if (g >= G) return;
    int i = picked[g];
    float di = dis[i];
    float a = b2f(h2c[(size_t)pos1[i] * 256 + t]);
    int e1 = rowptr[i + 1];
    for (int e = rowptr[i]; e < e1; e++) {
        a += b2f(h2c[(size_t)pos1[col[e]] * 256 + t]);
    }
    agg[t] = di * a;
    __syncthreads();
    int c = t & 15, seg = t >> 4;
    float p = 0.f;
#pragma unroll
    for (int kk = 0; kk < 16; kk++) {
        int k = seg * 16 + kk;
        p += agg[k] * W3[k * 16 + c];
    }
    red[t] = p;
    __syncthreads();
    if (t < 16) {
        float sres = 0.f;
#pragma unroll
        for (int ss = 0; ss < 16; ss++) sres += red[ss * 16 + t];
        out[g * 16 + t] = sres + b3[t];
    }
}

// ---------------- launch ----------------

extern "C" void kernel_launch(void* const* d_in, const int* in_sizes, int n_in,
                              void* d_out, int out_size, void* d_ws, size_t ws_size,
                              hipStream_t stream) {
    const float* x   = (const float*)d_in[0];
    const int* ei    = (const int*)d_in[1];
    const int* batch = (const int*)d_in[2];
    const float* W1  = (const float*)d_in[3];
    const float* b1  = (const float*)d_in[4];
    const float* W2  = (const float*)d_in[5];
    const float* b2  = (const float*)d_in[6];
    const float* W3  = (const float*)d_in[7];
    const float* b3  = (const float*)d_in[8];

    const int IN = 128, H = 256, OUT = 16;
    int N = in_sizes[0] / IN;
    int E = in_sizes[1] / 2;
    int G = out_size / OUT;
    const int* srcp = ei;
    const int* dstp = ei + E;

    char* p = (char*)d_ws;
    auto carve = [&](size_t bytes) {
        char* q = p;
        p += (bytes + 255) & ~(size_t)255;
        return q;
    };
    // zeroed region: cnt, flag1, flag2 (carved contiguously)
    int*    cnt    = (int*)carve((size_t)N * 4);
    int*    flag1  = (int*)carve((size_t)N * 4);
    int*    flag2  = (int*)carve((size_t)N * 4);
    char*   zend   = p;
    float*  dis    = (float*)carve((size_t)N * 4);
    int*    rowptr = (int*)carve(((size_t)N + 1) * 4);
    int*    cur    = (int*)carve((size_t)N * 4);
    int*    bsums  = (int*)carve(1024 * 4);
    int2*   cbsums = (int2*)carve(1024 * 8);
    int*    counts = (int*)carve(256);
    int*    picked = (int*)carve((size_t)G * 4);
    int*    pos1   = (int*)carve((size_t)N * 4);
    int*    pos2   = (int*)carve((size_t)N * 4);
    int*    list1  = (int*)carve((size_t)N * 4);
    int*    list2  = (int*)carve((size_t)N * 4);
    int*    col    = (int*)carve((size_t)E * 4);
    ushort* W1t    = (ushort*)carve((size_t)256 * 128 * 2);
    ushort* W2t    = (ushort*)carve((size_t)256 * 256 * 2);
    ushort* RA     = (ushort*)carve((size_t)N * H * 2);  // aggXc, then agg1c
    ushort* RB     = (ushort*)carve((size_t)N * H * 2);  // h1c, then h2c

    ushort* aggXc = RA;   // [M2][128]
    ushort* agg1c = RA;   // [M1][256] (aggXc dead after gemm1)
    ushort* h1c   = RB;   // [M2][256]
    ushort* h2c   = RB;   // [M1][256] (h1c dead after agg2)

    int nb = (N + 1023) / 1024;

    hipMemsetAsync(cnt, 0, (size_t)(zend - (char*)cnt), stream);

    // CSR build + degrees + roots
    int cpN = (E > N ? E : N);
    count_pick<<<(cpN + 255) / 256, 256, 0, stream>>>(dstp, cnt, E, batch, picked, N);
    scan_phase1<<<nb, 256, 0, stream>>>(cnt, bsums, dis, N);
    scan_phase2<<<1, 1024, 0, stream>>>(bsums, nb);
    scan_phase3<<<nb, 256, 0, stream>>>(cnt, bsums, rowptr, cur, N, E);
    fill_kernel<<<(E + 255) / 256, 256, 0, stream>>>(srcp, dstp, cur, col, E);

    // frontier: S1 = roots U N(roots); S2 = S1 U N(S1)
    frontier1<<<(G * 64 + 255) / 256, 256, 0, stream>>>(picked, rowptr, col, flag1, G);
    frontier2<<<(N + 255) / 256, 256, 0, stream>>>(rowptr, col, flag1, flag2, N);

    // deterministic compaction: pos1/pos2 maps, list1/list2, M1/M2
    cscan1<<<nb, 256, 0, stream>>>(flag1, flag2, cbsums, N);
    cscan2<<<1, 1024, 0, stream>>>(cbsums, counts, nb);
    cscan3<<<nb, 256, 0, stream>>>(flag1, flag2, cbsums, pos1, pos2, list1, list2, N);

    // weights
    wtrans2<<<(98304 + 255) / 256, 256, 0, stream>>>(W1, W1t, W2, W2t);

    // layer 1 on S2: aggXc = dis*(sum dis_s*x[s] + dis_i*x[i]); h1c = dis*leaky(aggXc@W1 + b1)
    aggx_c<<<512, 256, 0, stream>>>(x, dis, rowptr, col, list2, counts, aggXc);
    gemm_c<128><<<256, 512, 0, stream>>>(aggXc, W1t, b1, dis, list2, counts, 1, h1c);

    // layer 2 on S1: agg1c = dis*(sum h1c); h2c = dis*leaky(agg1c@W2 + b2)
    agg2_c<<<128, 256, 0, stream>>>(h1c, dis, rowptr, col, list1, pos2, counts, agg1c);
    gemm_c<256><<<64, 512, 0, stream>>>(agg1c, W2t, b2, dis, list1, counts, 0, h2c);

    // layer 3 at roots
    final_c<<<G, 256, 0, stream>>>(h2c, dis, rowptr, col, picked, pos1, W3, b3, (float*)d_out, G);
}

// Round 8
// 146.260 us; speedup vs baseline: 1.9773x; 1.3257x over previous
//
#include <hip/hip_runtime.h>

#define NEG_SLOPE 0.01f

using short8 = __attribute__((ext_vector_type(8))) short;
using f32x4  = __attribute__((ext_vector_type(4))) float;

__device__ inline float b2f(ushort u) {
    union { unsigned u; float f; } x; x.u = ((unsigned)u) << 16; return x.f;
}
__device__ inline ushort f2b(float f) {
    union { float f; unsigned u; } x; x.f = f;
    unsigned r = x.u + 0x7FFFu + ((x.u >> 16) & 1u);  // RNE
    return (ushort)(r >> 16);
}
__device__ inline void gload16(const void* g, void* l) {
    __builtin_amdgcn_global_load_lds((__attribute__((address_space(1))) void*)g,
                                     (__attribute__((address_space(3))) void*)l, 16, 0, 0);
}

// ---------------- degree count + root pick/flag ----------------

__global__ void count_pick(const int* __restrict__ dst, int* __restrict__ cnt, int E,
                           const int* __restrict__ batch, int* __restrict__ picked,
                           int* __restrict__ rootflag, int N) {
    int i = blockIdx.x * blockDim.x + threadIdx.x;
    if (i < E) atomicAdd(&cnt[dst[i]], 1);
    if (i < N) {
        if (i == 0 || batch[i] != batch[i - 1]) { picked[batch[i]] = i; rootflag[i] = 1; }
    }
}

// ---------------- frontier marking from the edge list (no CSR needed) ----------------
// S1 = roots U {src : dst in roots}; S2 = S1 U {src : dst in S1}.

__global__ void frontier1e(const int* __restrict__ src, const int* __restrict__ dst,
                           const int* __restrict__ rootflag, int* __restrict__ flag1,
                           int E, int N) {
    int i = blockIdx.x * blockDim.x + threadIdx.x;
    if (i < N && rootflag[i]) flag1[i] = 1;
    if (i < E && rootflag[dst[i]]) flag1[src[i]] = 1;
}

__global__ void frontier2e(const int* __restrict__ src, const int* __restrict__ dst,
                           const int* __restrict__ flag1, int* __restrict__ flag2,
                           int E, int N) {
    int i = blockIdx.x * blockDim.x + threadIdx.x;
    if (i < N && flag1[i]) flag2[i] = 1;
    if (i < E && flag1[dst[i]]) flag2[src[i]] = 1;
}

// ---------------- triple scan: channels (cnt2 = flag2?cnt:0, flag1, flag2) ----------------
// Produces: dis (fused), rowptr/cur over masked degrees, pos1/list1, pos2/list2, M1/M2.

__global__ __launch_bounds__(256) void tscan1(const int* __restrict__ cnt,
                                              const int* __restrict__ f1,
                                              const int* __restrict__ f2,
                                              int4* __restrict__ bsums,
                                              float* __restrict__ dis, int N) {
    __shared__ int l0[256], l1[256], l2[256];
    int b = blockIdx.x, t = threadIdx.x;
    int base = b * 1024 + t * 4;
    int c[4] = {0,0,0,0}, a1[4] = {0,0,0,0}, a2[4] = {0,0,0,0};
    if (base + 3 < N) {
        int4 q = *(const int4*)(cnt + base); c[0]=q.x; c[1]=q.y; c[2]=q.z; c[3]=q.w;
        int4 u = *(const int4*)(f1 + base);  a1[0]=u.x; a1[1]=u.y; a1[2]=u.z; a1[3]=u.w;
        int4 v = *(const int4*)(f2 + base);  a2[0]=v.x; a2[1]=v.y; a2[2]=v.z; a2[3]=v.w;
    } else {
        for (int i = 0; i < 4; i++) if (base + i < N) {
            c[i] = cnt[base + i]; a1[i] = f1[base + i]; a2[i] = f2[base + i];
        }
    }
#pragma unroll
    for (int i = 0; i < 4; i++)
        if (base + i < N) dis[base + i] = rsqrtf((float)c[i] + 1.0f);
    int s0 = 0, s1 = 0, s2 = 0;
#pragma unroll
    for (int i = 0; i < 4; i++) { s0 += a2[i] ? c[i] : 0; s1 += a1[i]; s2 += a2[i]; }
    l0[t] = s0; l1[t] = s1; l2[t] = s2;
    __syncthreads();
    for (int off = 128; off > 0; off >>= 1) {
        if (t < off) { l0[t] += l0[t + off]; l1[t] += l1[t + off]; l2[t] += l2[t + off]; }
        __syncthreads();
    }
    if (t == 0) bsums[b] = make_int4(l0[0], l1[0], l2[0], 0);
}

__global__ __launch_bounds__(1024) void tscan2(int4* __restrict__ bsums, int* __restrict__ counts,
                                               int* __restrict__ rowptr, int N, int nb) {
    __shared__ int l0[1024], l1[1024], l2[1024];
    int t = threadIdx.x;
    int v0 = 0, v1 = 0, v2 = 0;
    if (t < nb) { int4 v = bsums[t]; v0 = v.x; v1 = v.y; v2 = v.z; }
    l0[t] = v0; l1[t] = v1; l2[t] = v2;
    __syncthreads();
    for (int off = 1; off < 1024; off <<= 1) {
        int u0 = (t >= off) ? l0[t - off] : 0;
        int u1 = (t >= off) ? l1[t - off] : 0;
        int u2 = (t >= off) ? l2[t - off] : 0;
        __syncthreads();
        l0[t] += u0; l1[t] += u1; l2[t] += u2;
        __syncthreads();
    }
    if (t < nb) bsums[t] = make_int4(l0[t] - v0, l1[t] - v1, l2[t] - v2, 0);  // exclusive
    if (t == 1023) {
        counts[0] = l1[1023];   // M1
        counts[1] = l2[1023];   // M2
        rowptr[N] = l0[1023];   // total masked edges
    }
}

__global__ __launch_bounds__(256) void tscan3(const int* __restrict__ cnt,
                                              const int* __restrict__ f1,
                                              const int* __restrict__ f2,
                                              const int4* __restrict__ bsums,
                                              int* __restrict__ rowptr, int* __restrict__ cur,
                                              int* __restrict__ pos1, int* __restrict__ pos2,
                                              int* __restrict__ list1, int* __restrict__ list2,
                                              int N) {
    __shared__ int l0[256], l1[256], l2[256];
    int b = blockIdx.x, t = threadIdx.x;
    int base = b * 1024 + t * 4;
    int c[4] = {0,0,0,0}, a1[4] = {0,0,0,0}, a2[4] = {0,0,0,0};
    if (base + 3 < N) {
        int4 q = *(const int4*)(cnt + base); c[0]=q.x; c[1]=q.y; c[2]=q.z; c[3]=q.w;
        int4 u = *(const int4*)(f1 + base);  a1[0]=u.x; a1[1]=u.y; a1[2]=u.z; a1[3]=u.w;
        int4 v = *(const int4*)(f2 + base);  a2[0]=v.x; a2[1]=v.y; a2[2]=v.z; a2[3]=v.w;
    } else {
        for (int i = 0; i < 4; i++) if (base + i < N) {
            c[i] = cnt[base + i]; a1[i] = f1[base + i]; a2[i] = f2[base + i];
        }
    }
    int m[4];
#pragma unroll
    for (int i = 0; i < 4; i++) m[i] = a2[i] ? c[i] : 0;
    int s0 = m[0] + m[1] + m[2] + m[3];
    int s1 = a1[0] + a1[1] + a1[2] + a1[3];
    int s2 = a2[0] + a2[1] + a2[2] + a2[3];
    l0[t] = s0; l1[t] = s1; l2[t] = s2;
    __syncthreads();
    for (int off = 1; off < 256; off <<= 1) {
        int u0 = (t >= off) ? l0[t - off] : 0;
        int u1 = (t >= off) ? l1[t - off] : 0;
        int u2 = (t >= off) ? l2[t - off] : 0;
        __syncthreads();
        l0[t] += u0; l1[t] += u1; l2[t] += u2;
        __syncthreads();
    }
    int4 bs = bsums[b];
    int run0 = bs.x + l0[t] - s0;
    int run1 = bs.y + l1[t] - s1;
    int run2 = bs.z + l2[t] - s2;
#pragma unroll
    for (int i = 0; i < 4; i++) {
        if (base + i < N) {
            rowptr[base + i] = run0;
            cur[base + i] = run0;
            if (a1[i]) { pos1[base + i] = run1; list1[run1] = base + i; }
            if (a2[i]) { pos2[base + i] = run2; list2[run2] = base + i; }
        }
        run0 += m[i]; run1 += a1[i]; run2 += a2[i];
    }
}

// ---------------- filtered CSR fill: only edges whose dst is in S2 ----------------

__global__ void fill_f(const int* __restrict__ src, const int* __restrict__ dst,
                       const int* __restrict__ flag2, int* __restrict__ cur,
                       int* __restrict__ col, int E) {
    int e = blockIdx.x * blockDim.x + threadIdx.x;
    if (e < E) {
        int d = dst[e];
        if (flag2[d]) {
            int pos = atomicAdd(&cur[d], 1);
            col[pos] = src[e];
        }
    }
}

// ---------------- weight transposes (bf16) ----------------

__global__ void wtrans2(const float* __restrict__ W1, ushort* __restrict__ W1t,
                        const float* __restrict__ W2, ushort* __restrict__ W2t) {
    int idx = blockIdx.x * blockDim.x + threadIdx.x;
    if (idx < 32768) {                       // W1t[n][k] = W1[k][n], K=128
        int n = idx >> 7, k = idx & 127;
        W1t[idx] = f2b(W1[k * 256 + n]);
    } else if (idx < 98304) {                // W2t[n][k] = W2[k][n], K=256
        int j = idx - 32768;
        int n = j >> 8, k = j & 255;
        W2t[j] = f2b(W2[k * 256 + n]);
    }
}

// ---------------- layer-1 aggregation on S2 (compact): from f32 x directly ----------------

__global__ __launch_bounds__(256) void aggx_c(const float* __restrict__ x,
                                              const float* __restrict__ dis,
                                              const int* __restrict__ rowptr,
                                              const int* __restrict__ col,
                                              const int* __restrict__ list2,
                                              const int* __restrict__ counts,
                                              ushort* __restrict__ aggXc) {
    const int M2 = counts[1];
    int wave = blockIdx.x * 4 + (threadIdx.x >> 6);
    int lane = threadIdx.x & 63;
    int li = lane & 31, sub = lane >> 5;
    int stride = gridDim.x * 8;  // rows per sweep (2 rows/wave)
    const float* xp = x + li * 4;
    for (int p = wave * 2 + sub; p < M2; p += stride) {
        int node = list2[p];
        float di = dis[node];
        float4 sv = *(const float4*)(xp + (size_t)node * 128);
        float a0 = di * sv.x, a1 = di * sv.y, a2 = di * sv.z, a3 = di * sv.w;
        int e1 = rowptr[node + 1];
        for (int e = rowptr[node]; e < e1; e++) {
            int s = col[e];
            float w = dis[s];
            float4 v = *(const float4*)(xp + (size_t)s * 128);
            a0 += w * v.x; a1 += w * v.y; a2 += w * v.z; a3 += w * v.w;
        }
        ushort4 o;
        o.x = f2b(di * a0); o.y = f2b(di * a1); o.z = f2b(di * a2); o.w = f2b(di * a3);
        *(ushort4*)(aggXc + (size_t)p * 128 + li * 4) = o;
    }
}

// ---------------- layer-2 aggregation on S1 (compact), h1c indexed via pos2 ----------------

__global__ __launch_bounds__(256) void agg2_c(const ushort* __restrict__ h1c,
                                              const float* __restrict__ dis,
                                              const int* __restrict__ rowptr,
                                              const int* __restrict__ col,
                                              const int* __restrict__ list1,
                                              const int* __restrict__ pos2,
                                              const int* __restrict__ counts,
                                              ushort* __restrict__ agg1c) {
    const int M1 = counts[0];
    int wave = blockIdx.x * 4 + (threadIdx.x >> 6);
    int lane = threadIdx.x & 63;
    int li = lane & 31, sub = lane >> 5;
    int stride = gridDim.x * 8;
    const ushort* hp = h1c + (size_t)li * 8;
    for (int p = wave * 2 + sub; p < M1; p += stride) {
        int i = list1[p];
        float di = dis[i];
        float a[8];
        {
            short8 v = *(const short8*)(hp + (size_t)pos2[i] * 256);
#pragma unroll
            for (int j = 0; j < 8; j++) a[j] = b2f((ushort)v[j]);
        }
        int e1 = rowptr[i + 1];
        for (int e = rowptr[i]; e < e1; e++) {
            short8 v = *(const short8*)(hp + (size_t)pos2[col[e]] * 256);
#pragma unroll
            for (int j = 0; j < 8; j++) a[j] += b2f((ushort)v[j]);
        }
        short8 o;
#pragma unroll
        for (int j = 0; j < 8; j++) o[j] = (short)f2b(di * a[j]);
        *(short8*)(agg1c + (size_t)p * 256 + li * 8) = o;
    }
}

// ---------------- compact MFMA GEMM: C[M x 256] = bf16( dis[list[row]] * leaky(A @ Bt^T + bias) ) ----------------

template <int K>
__global__ __launch_bounds__(512) void gemm_c(const ushort* __restrict__ A,
                                              const ushort* __restrict__ Bt,
                                              const float* __restrict__ bias,
                                              const float* __restrict__ dis,
                                              const int* __restrict__ list,
                                              const int* __restrict__ counts, int which,
                                              ushort* __restrict__ C) {
    __shared__ ushort As[128 * 64];   // 16 KB
    __shared__ ushort Bs[256 * 64];   // 32 KB
    const int M = counts[which];
    const int t = threadIdx.x;
    const int lane = t & 63;
    const int w = t >> 6;
    const int wm = w >> 2, wn = w & 3;

    for (int tile = blockIdx.x; tile * 128 < M; tile += gridDim.x) {
        const int row0 = tile * 128;
        f32x4 acc[4][4] = {};

        for (int kt = 0; kt < K / 64; kt++) {
#pragma unroll
            for (int it = 0; it < 2; it++) {           // As: 1024 chunks
                int q = it * 512 + t;
                int r = q >> 3, c = q & 7;
                int cs = c ^ (r & 7);
                int ga = min(row0 + r, M - 1);
                gload16(A + (size_t)ga * K + kt * 64 + cs * 8, &As[q * 8]);
            }
#pragma unroll
            for (int it = 0; it < 4; it++) {           // Bs: 2048 chunks
                int q = it * 512 + t;
                int r = q >> 3, c = q & 7;
                int cs = c ^ (r & 7);
                gload16(Bt + (size_t)r * K + kt * 64 + cs * 8, &Bs[q * 8]);
            }
            __syncthreads();
#pragma unroll
            for (int ks = 0; ks < 2; ks++) {
                short8 a[4], b[4];
                int cc = ks * 4 + (lane >> 4);
#pragma unroll
                for (int m = 0; m < 4; m++) {
                    int R = wm * 64 + m * 16 + (lane & 15);
                    a[m] = *(const short8*)&As[R * 64 + ((cc ^ (R & 7)) * 8)];
                }
#pragma unroll
                for (int n = 0; n < 4; n++) {
                    int R = wn * 64 + n * 16 + (lane & 15);
                    b[n] = *(const short8*)&Bs[R * 64 + ((cc ^ (R & 7)) * 8)];
                }
#pragma unroll
                for (int m = 0; m < 4; m++)
#pragma unroll
                    for (int n = 0; n < 4; n++)
                        acc[m][n] = __builtin_amdgcn_mfma_f32_16x16x32_bf16(a[m], b[n], acc[m][n], 0, 0, 0);
            }
            __syncthreads();
        }

        // epilogue: C/D layout col=lane&15, row=(lane>>4)*4+j
#pragma unroll
        for (int m = 0; m < 4; m++) {
#pragma unroll
            for (int j = 0; j < 4; j++) {
                int grow = row0 + wm * 64 + m * 16 + (lane >> 4) * 4 + j;
                if (grow >= M) continue;
                float dr = dis[list[grow]];
#pragma unroll
                for (int n = 0; n < 4; n++) {
                    int gcol = wn * 64 + n * 16 + (lane & 15);
                    float v = acc[m][n][j] + bias[gcol];
                    v = v > 0.f ? v : NEG_SLOPE * v;
                    C[(size_t)grow * 256 + gcol] = f2b(v * dr);
                }
            }
        }
    }
}

// ---------------- final: per graph, aggregate h2c at the root (via pos1), then 256x16 GEMM ----------------

__global__ __launch_bounds__(256) void final_c(const ushort* __restrict__ h2c,
                                               const float* __restrict__ dis,
                                               const int* __restrict__ rowptr,
                                               const int* __restrict__ col,
                                               const int* __restrict__ picked,
                                               const int* __restrict__ pos1,
                                               const float* __restrict__ W3,
                                               const float* __restrict__ b3,
                                               float* __restrict__ out, int G) {
    __shared__ float agg[256];
    __shared__ float red[256];
    int g = blockIdx.x;
    int t = threadIdx.x;
    if (g >= G) return;
    int i = picked[g];
    float di = dis[i];
    float a = b2f(h2c[(size_t)pos1[i] * 256 + t]);
    int e1 = rowptr[i + 1];
    for (int e = rowptr[i]; e < e1; e++) {
        a += b2f(h2c[(size_t)pos1[col[e]] * 256 + t]);
    }
    agg[t] = di * a;
    __syncthreads();
    int c = t & 15, seg = t >> 4;
    float p = 0.f;
#pragma unroll
    for (int kk = 0; kk < 16; kk++) {
        int k = seg * 16 + kk;
        p += agg[k] * W3[k * 16 + c];
    }
    red[t] = p;
    __syncthreads();
    if (t < 16) {
        float sres = 0.f;
#pragma unroll
        for (int ss = 0; ss < 16; ss++) sres += red[ss * 16 + t];
        out[g * 16 + t] = sres + b3[t];
    }
}

// ---------------- launch ----------------

extern "C" void kernel_launch(void* const* d_in, const int* in_sizes, int n_in,
                              void* d_out, int out_size, void* d_ws, size_t ws_size,
                              hipStream_t stream) {
    const float* x   = (const float*)d_in[0];
    const int* ei    = (const int*)d_in[1];
    const int* batch = (const int*)d_in[2];
    const float* W1  = (const float*)d_in[3];
    const float* b1  = (const float*)d_in[4];
    const float* W2  = (const float*)d_in[5];
    const float* b2  = (const float*)d_in[6];
    const float* W3  = (const float*)d_in[7];
    const float* b3  = (const float*)d_in[8];

    const int IN = 128, H = 256, OUT = 16;
    int N = in_sizes[0] / IN;
    int E = in_sizes[1] / 2;
    int G = out_size / OUT;
    const int* srcp = ei;
    const int* dstp = ei + E;

    char* p = (char*)d_ws;
    auto carve = [&](size_t bytes) {
        char* q = p;
        p += (bytes + 255) & ~(size_t)255;
        return q;
    };
    // zeroed region: cnt, flag1, flag2, rootflag (carved contiguously)
    int*    cnt      = (int*)carve((size_t)N * 4);
    int*    flag1    = (int*)carve((size_t)N * 4);
    int*    flag2    = (int*)carve((size_t)N * 4);
    int*    rootflag = (int*)carve((size_t)N * 4);
    char*   zend     = p;
    float*  dis    = (float*)carve((size_t)N * 4);
    int*    rowptr = (int*)carve(((size_t)N + 1) * 4);
    int*    cur    = (int*)carve((size_t)N * 4);
    int4*   tbsums = (int4*)carve(1024 * 16);
    int*    counts = (int*)carve(256);
    int*    picked = (int*)carve((size_t)G * 4);
    int*    pos1   = (int*)carve((size_t)N * 4);
    int*    pos2   = (int*)carve((size_t)N * 4);
    int*    list1  = (int*)carve((size_t)N * 4);
    int*    list2  = (int*)carve((size_t)N * 4);
    int*    col    = (int*)carve((size_t)E * 4);
    ushort* W1t    = (ushort*)carve((size_t)256 * 128 * 2);
    ushort* W2t    = (ushort*)carve((size_t)256 * 256 * 2);
    ushort* RA     = (ushort*)carve((size_t)N * H * 2);  // aggXc, then agg1c
    ushort* RB     = (ushort*)carve((size_t)N * H * 2);  // h1c, then h2c

    ushort* aggXc = RA;   // [M2][128]
    ushort* agg1c = RA;   // [M1][256] (aggXc dead after gemm1)
    ushort* h1c   = RB;   // [M2][256]
    ushort* h2c   = RB;   // [M1][256] (h1c dead after agg2)

    int nb = (N + 1023) / 1024;
    int cpN = (E > N ? E : N);

    hipMemsetAsync(cnt, 0, (size_t)(zend - (char*)cnt), stream);

    // degrees + roots
    count_pick<<<(cpN + 255) / 256, 256, 0, stream>>>(dstp, cnt, E, batch, picked, rootflag, N);

    // frontiers from the edge list
    frontier1e<<<(cpN + 255) / 256, 256, 0, stream>>>(srcp, dstp, rootflag, flag1, E, N);
    frontier2e<<<(cpN + 255) / 256, 256, 0, stream>>>(srcp, dstp, flag1, flag2, E, N);

    // fused triple scan: dis, masked rowptr/cur, pos/list maps, M1/M2
    tscan1<<<nb, 256, 0, stream>>>(cnt, flag1, flag2, tbsums, dis, N);
    tscan2<<<1, 1024, 0, stream>>>(tbsums, counts, rowptr, N, nb);
    tscan3<<<nb, 256, 0, stream>>>(cnt, flag1, flag2, tbsums, rowptr, cur, pos1, pos2, list1, list2, N);

    // filtered CSR fill (only dst in S2)
    fill_f<<<(E + 255) / 256, 256, 0, stream>>>(srcp, dstp, flag2, cur, col, E);

    // weights
    wtrans2<<<(98304 + 255) / 256, 256, 0, stream>>>(W1, W1t, W2, W2t);

    // layer 1 on S2: aggXc = dis*(sum dis_s*x[s] + dis_i*x[i]); h1c = dis*leaky(aggXc@W1 + b1)
    aggx_c<<<512, 256, 0, stream>>>(x, dis, rowptr, col, list2, counts, aggXc);
    gemm_c<128><<<256, 512, 0, stream>>>(aggXc, W1t, b1, dis, list2, counts, 1, h1c);

    // layer 2 on S1: agg1c = dis*(sum h1c); h2c = dis*leaky(agg1c@W2 + b2)
    agg2_c<<<128, 256, 0, stream>>>(h1c, dis, rowptr, col, list1, pos2, counts, agg1c);
    gemm_c<256><<<64, 512, 0, stream>>>(agg1c, W2t, b2, dis, list1, counts, 0, h2c);

    // layer 3 at roots
    final_c<<<G, 256, 0, stream>>>(h2c, dis, rowptr, col, picked, pos1, W3, b3, (float*)d_out, G);
}

// Round 9
// 134.092 us; speedup vs baseline: 2.1567x; 1.0907x over previous
//
#include <hip/hip_runtime.h>

#define NEG_SLOPE 0.01f

using short8 = __attribute__((ext_vector_type(8))) short;
using f32x4  = __attribute__((ext_vector_type(4))) float;

__device__ inline float b2f(ushort u) {
    union { unsigned u; float f; } x; x.u = ((unsigned)u) << 16; return x.f;
}
__device__ inline ushort f2b(float f) {
    union { float f; unsigned u; } x; x.f = f;
    unsigned r = x.u + 0x7FFFu + ((x.u >> 16) & 1u);  // RNE
    return (ushort)(r >> 16);
}
__device__ inline void gload16(const void* g, void* l) {
    __builtin_amdgcn_global_load_lds((__attribute__((address_space(1))) void*)g,
                                     (__attribute__((address_space(3))) void*)l, 16, 0, 0);
}

// ---------------- init: zero counters/flags, mark roots, pick root per graph ----------------

__global__ void init_kernel(const int* __restrict__ batch, int* __restrict__ cnt,
                            int* __restrict__ flag1, int* __restrict__ flag2,
                            int* __restrict__ rootflag, int* __restrict__ picked, int N) {
    int i = blockIdx.x * blockDim.x + threadIdx.x;
    if (i >= N) return;
    cnt[i] = 0;
    int root = (i == 0) || (batch[i] != batch[i - 1]);
    flag1[i] = root;   // roots are in S1
    flag2[i] = 0;
    rootflag[i] = root;
    if (root) picked[batch[i]] = i;
}

// ---------------- fused E-pass 1: degree count + frontier1 (flag1 |= src of root-edges) ----------------
// 4 edges per thread, int4 loads for MLP.

__global__ void count_f1(const int* __restrict__ src, const int* __restrict__ dst,
                         const int* __restrict__ rootflag, int* __restrict__ cnt,
                         int* __restrict__ flag1, int E) {
    int i = blockIdx.x * blockDim.x + threadIdx.x;
    int e0 = i * 4;
    if (e0 + 3 < E) {
        int4 dq = *(const int4*)(dst + e0);
        int r0 = rootflag[dq.x], r1 = rootflag[dq.y], r2 = rootflag[dq.z], r3 = rootflag[dq.w];
        atomicAdd(&cnt[dq.x], 1);
        atomicAdd(&cnt[dq.y], 1);
        atomicAdd(&cnt[dq.z], 1);
        atomicAdd(&cnt[dq.w], 1);
        if (r0 | r1 | r2 | r3) {
            int4 sq = *(const int4*)(src + e0);
            if (r0) flag1[sq.x] = 1;
            if (r1) flag1[sq.y] = 1;
            if (r2) flag1[sq.z] = 1;
            if (r3) flag1[sq.w] = 1;
        }
    } else if (e0 < E) {
        for (int e = e0; e < E; e++) {
            int d = dst[e];
            atomicAdd(&cnt[d], 1);
            if (rootflag[d]) flag1[src[e]] = 1;
        }
    }
}

// ---------------- E-pass 2: frontier2 (flag2 = S1 U {src : dst in S1}) ----------------

__global__ void frontier2v(const int* __restrict__ src, const int* __restrict__ dst,
                           const int* __restrict__ flag1, int* __restrict__ flag2,
                           int E, int N) {
    int i = blockIdx.x * blockDim.x + threadIdx.x;
    int e0 = i * 4;
    if (e0 + 3 < E) {
        int4 dq = *(const int4*)(dst + e0);
        int f0 = flag1[dq.x], f1 = flag1[dq.y], f2 = flag1[dq.z], f3 = flag1[dq.w];
        if (f0 | f1 | f2 | f3) {
            int4 sq = *(const int4*)(src + e0);
            if (f0) flag2[sq.x] = 1;
            if (f1) flag2[sq.y] = 1;
            if (f2) flag2[sq.z] = 1;
            if (f3) flag2[sq.w] = 1;
        }
    } else if (e0 < E) {
        for (int e = e0; e < E; e++) if (flag1[dst[e]]) flag2[src[e]] = 1;
    }
    if (i < N && flag1[i]) flag2[i] = 1;
}

// ---------------- triple scan (channels: masked cnt, flag1, flag2) + fused dis + wtrans ----------------

__global__ __launch_bounds__(256) void tscan1w(const int* __restrict__ cnt,
                                               const int* __restrict__ f1,
                                               const int* __restrict__ f2,
                                               int4* __restrict__ bsums,
                                               float* __restrict__ dis, int N, int nb,
                                               const float* __restrict__ W1, ushort* __restrict__ W1t,
                                               const float* __restrict__ W2, ushort* __restrict__ W2t) {
    __shared__ int l0[256], l1[256], l2[256];
    int b = blockIdx.x, t = threadIdx.x;
    if (b < nb) {
        int base = b * 1024 + t * 4;
        int c[4] = {0,0,0,0}, a1[4] = {0,0,0,0}, a2[4] = {0,0,0,0};
        if (base + 3 < N) {
            int4 q = *(const int4*)(cnt + base); c[0]=q.x; c[1]=q.y; c[2]=q.z; c[3]=q.w;
            int4 u = *(const int4*)(f1 + base);  a1[0]=u.x; a1[1]=u.y; a1[2]=u.z; a1[3]=u.w;
            int4 v = *(const int4*)(f2 + base);  a2[0]=v.x; a2[1]=v.y; a2[2]=v.z; a2[3]=v.w;
        } else {
            for (int i = 0; i < 4; i++) if (base + i < N) {
                c[i] = cnt[base + i]; a1[i] = f1[base + i]; a2[i] = f2[base + i];
            }
        }
#pragma unroll
        for (int i = 0; i < 4; i++)
            if (base + i < N) dis[base + i] = rsqrtf((float)c[i] + 1.0f);
        int s0 = 0, s1 = 0, s2 = 0;
#pragma unroll
        for (int i = 0; i < 4; i++) { s0 += a2[i] ? c[i] : 0; s1 += a1[i]; s2 += a2[i]; }
        l0[t] = s0; l1[t] = s1; l2[t] = s2;
        __syncthreads();
        for (int off = 128; off > 0; off >>= 1) {
            if (t < off) { l0[t] += l0[t + off]; l1[t] += l1[t + off]; l2[t] += l2[t + off]; }
            __syncthreads();
        }
        if (t == 0) bsums[b] = make_int4(l0[0], l1[0], l2[0], 0);
    }
    // fused weight transpose (independent work), grid-strided
    for (int idx = b * 256 + t; idx < 98304; idx += gridDim.x * 256) {
        if (idx < 32768) {                   // W1t[n][k] = W1[k][n], K=128
            int n = idx >> 7, k = idx & 127;
            W1t[idx] = f2b(W1[k * 256 + n]);
        } else {                             // W2t[n][k] = W2[k][n], K=256
            int j = idx - 32768;
            int n = j >> 8, k = j & 255;
            W2t[j] = f2b(W2[k * 256 + n]);
        }
    }
}

__global__ __launch_bounds__(1024) void tscan2(int4* __restrict__ bsums, int* __restrict__ counts,
                                               int* __restrict__ rowptr, int N, int nb) {
    __shared__ int l0[1024], l1[1024], l2[1024];
    int t = threadIdx.x;
    int v0 = 0, v1 = 0, v2 = 0;
    if (t < nb) { int4 v = bsums[t]; v0 = v.x; v1 = v.y; v2 = v.z; }
    l0[t] = v0; l1[t] = v1; l2[t] = v2;
    __syncthreads();
    for (int off = 1; off < 1024; off <<= 1) {
        int u0 = (t >= off) ? l0[t - off] : 0;
        int u1 = (t >= off) ? l1[t - off] : 0;
        int u2 = (t >= off) ? l2[t - off] : 0;
        __syncthreads();
        l0[t] += u0; l1[t] += u1; l2[t] += u2;
        __syncthreads();
    }
    if (t < nb) bsums[t] = make_int4(l0[t] - v0, l1[t] - v1, l2[t] - v2, 0);  // exclusive
    if (t == 1023) {
        counts[0] = l1[1023];   // M1
        counts[1] = l2[1023];   // M2
        rowptr[N] = l0[1023];   // total masked edges
    }
}

__global__ __launch_bounds__(256) void tscan3(const int* __restrict__ cnt,
                                              const int* __restrict__ f1,
                                              const int* __restrict__ f2,
                                              const int4* __restrict__ bsums,
                                              int* __restrict__ rowptr, int* __restrict__ cur,
                                              int* __restrict__ pos1, int* __restrict__ pos2,
                                              int* __restrict__ list1, int* __restrict__ list2,
                                              int N) {
    __shared__ int l0[256], l1[256], l2[256];
    int b = blockIdx.x, t = threadIdx.x;
    int base = b * 1024 + t * 4;
    int c[4] = {0,0,0,0}, a1[4] = {0,0,0,0}, a2[4] = {0,0,0,0};
    if (base + 3 < N) {
        int4 q = *(const int4*)(cnt + base); c[0]=q.x; c[1]=q.y; c[2]=q.z; c[3]=q.w;
        int4 u = *(const int4*)(f1 + base);  a1[0]=u.x; a1[1]=u.y; a1[2]=u.z; a1[3]=u.w;
        int4 v = *(const int4*)(f2 + base);  a2[0]=v.x; a2[1]=v.y; a2[2]=v.z; a2[3]=v.w;
    } else {
        for (int i = 0; i < 4; i++) if (base + i < N) {
            c[i] = cnt[base + i]; a1[i] = f1[base + i]; a2[i] = f2[base + i];
        }
    }
    int m[4];
#pragma unroll
    for (int i = 0; i < 4; i++) m[i] = a2[i] ? c[i] : 0;
    int s0 = m[0] + m[1] + m[2] + m[3];
    int s1 = a1[0] + a1[1] + a1[2] + a1[3];
    int s2 = a2[0] + a2[1] + a2[2] + a2[3];
    l0[t] = s0; l1[t] = s1; l2[t] = s2;
    __syncthreads();
    for (int off = 1; off < 256; off <<= 1) {
        int u0 = (t >= off) ? l0[t - off] : 0;
        int u1 = (t >= off) ? l1[t - off] : 0;
        int u2 = (t >= off) ? l2[t - off] : 0;
        __syncthreads();
        l0[t] += u0; l1[t] += u1; l2[t] += u2;
        __syncthreads();
    }
    int4 bs = bsums[b];
    int run0 = bs.x + l0[t] - s0;
    int run1 = bs.y + l1[t] - s1;
    int run2 = bs.z + l2[t] - s2;
#pragma unroll
    for (int i = 0; i < 4; i++) {
        if (base + i < N) {
            rowptr[base + i] = run0;
            cur[base + i] = run0;
            if (a1[i]) { pos1[base + i] = run1; list1[run1] = base + i; }
            if (a2[i]) { pos2[base + i] = run2; list2[run2] = base + i; }
        }
        run0 += m[i]; run1 += a1[i]; run2 += a2[i];
    }
}

// ---------------- E-pass 3: filtered CSR fill (only edges whose dst is in S2) ----------------

__global__ void fill_fv(const int* __restrict__ src, const int* __restrict__ dst,
                        const int* __restrict__ flag2, int* __restrict__ cur,
                        int* __restrict__ col, int E) {
    int i = blockIdx.x * blockDim.x + threadIdx.x;
    int e0 = i * 4;
    if (e0 + 3 < E) {
        int4 dq = *(const int4*)(dst + e0);
        int f0 = flag2[dq.x], f1 = flag2[dq.y], f2 = flag2[dq.z], f3 = flag2[dq.w];
        if (f0 | f1 | f2 | f3) {
            int4 sq = *(const int4*)(src + e0);
            if (f0) col[atomicAdd(&cur[dq.x], 1)] = sq.x;
            if (f1) col[atomicAdd(&cur[dq.y], 1)] = sq.y;
            if (f2) col[atomicAdd(&cur[dq.z], 1)] = sq.z;
            if (f3) col[atomicAdd(&cur[dq.w], 1)] = sq.w;
        }
    } else if (e0 < E) {
        for (int e = e0; e < E; e++) {
            int d = dst[e];
            if (flag2[d]) col[atomicAdd(&cur[d], 1)] = src[e];
        }
    }
}

// ---------------- layer-1 aggregation on S2 (compact): from f32 x directly ----------------

__global__ __launch_bounds__(256) void aggx_c(const float* __restrict__ x,
                                              const float* __restrict__ dis,
                                              const int* __restrict__ rowptr,
                                              const int* __restrict__ col,
                                              const int* __restrict__ list2,
                                              const int* __restrict__ counts,
                                              ushort* __restrict__ aggXc) {
    const int M2 = counts[1];
    int wave = blockIdx.x * 4 + (threadIdx.x >> 6);
    int lane = threadIdx.x & 63;
    int li = lane & 31, sub = lane >> 5;
    int stride = gridDim.x * 8;  // rows per sweep (2 rows/wave)
    const float* xp = x + li * 4;
    for (int p = wave * 2 + sub; p < M2; p += stride) {
        int node = list2[p];
        float di = dis[node];
        float4 sv = *(const float4*)(xp + (size_t)node * 128);
        float a0 = di * sv.x, a1 = di * sv.y, a2 = di * sv.z, a3 = di * sv.w;
        int e = rowptr[node], e1 = rowptr[node + 1];
        for (; e + 2 <= e1; e += 2) {
            int s0 = col[e], s1 = col[e + 1];
            float w0 = dis[s0], w1 = dis[s1];
            float4 v0 = *(const float4*)(xp + (size_t)s0 * 128);
            float4 v1 = *(const float4*)(xp + (size_t)s1 * 128);
            a0 += w0 * v0.x + w1 * v1.x;
            a1 += w0 * v0.y + w1 * v1.y;
            a2 += w0 * v0.z + w1 * v1.z;
            a3 += w0 * v0.w + w1 * v1.w;
        }
        if (e < e1) {
            int s = col[e];
            float w = dis[s];
            float4 v = *(const float4*)(xp + (size_t)s * 128);
            a0 += w * v.x; a1 += w * v.y; a2 += w * v.z; a3 += w * v.w;
        }
        ushort4 o;
        o.x = f2b(di * a0); o.y = f2b(di * a1); o.z = f2b(di * a2); o.w = f2b(di * a3);
        *(ushort4*)(aggXc + (size_t)p * 128 + li * 4) = o;
    }
}

// ---------------- layer-2 aggregation on S1 (compact), h1c indexed via pos2 ----------------

__global__ __launch_bounds__(256) void agg2_c(const ushort* __restrict__ h1c,
                                              const float* __restrict__ dis,
                                              const int* __restrict__ rowptr,
                                              const int* __restrict__ col,
                                              const int* __restrict__ list1,
                                              const int* __restrict__ pos2,
                                              const int* __restrict__ counts,
                                              ushort* __restrict__ agg1c) {
    const int M1 = counts[0];
    int wave = blockIdx.x * 4 + (threadIdx.x >> 6);
    int lane = threadIdx.x & 63;
    int li = lane & 31, sub = lane >> 5;
    int stride = gridDim.x * 8;
    const ushort* hp = h1c + (size_t)li * 8;
    for (int p = wave * 2 + sub; p < M1; p += stride) {
        int i = list1[p];
        float di = dis[i];
        float a[8];
        {
            short8 v = *(const short8*)(hp + (size_t)pos2[i] * 256);
#pragma unroll
            for (int j = 0; j < 8; j++) a[j] = b2f((ushort)v[j]);
        }
        int e1 = rowptr[i + 1];
        for (int e = rowptr[i]; e < e1; e++) {
            short8 v = *(const short8*)(hp + (size_t)pos2[col[e]] * 256);
#pragma unroll
            for (int j = 0; j < 8; j++) a[j] += b2f((ushort)v[j]);
        }
        short8 o;
#pragma unroll
        for (int j = 0; j < 8; j++) o[j] = (short)f2b(di * a[j]);
        *(short8*)(agg1c + (size_t)p * 256 + li * 8) = o;
    }
}

// ---------------- compact MFMA GEMM: C[M x 256] = bf16( dis[list[row]] * leaky(A @ Bt^T + bias) ) ----------------

template <int K>
__global__ __launch_bounds__(512) void gemm_c(const ushort* __restrict__ A,
                                              const ushort* __restrict__ Bt,
                                              const float* __restrict__ bias,
                                              const float* __restrict__ dis,
                                              const int* __restrict__ list,
                                              const int* __restrict__ counts, int which,
                                              ushort* __restrict__ C) {
    __shared__ ushort As[128 * 64];   // 16 KB
    __shared__ ushort Bs[256 * 64];   // 32 KB
    const int M = counts[which];
    const int t = threadIdx.x;
    const int lane = t & 63;
    const int w = t >> 6;
    const int wm = w >> 2, wn = w & 3;

    for (int tile = blockIdx.x; tile * 128 < M; tile += gridDim.x) {
        const int row0 = tile * 128;
        f32x4 acc[4][4] = {};

        for (int kt = 0; kt < K / 64; kt++) {
#pragma unroll
            for (int it = 0; it < 2; it++) {           // As: 1024 chunks
                int q = it * 512 + t;
                int r = q >> 3, c = q & 7;
                int cs = c ^ (r & 7);
                int ga = min(row0 + r, M - 1);
                gload16(A + (size_t)ga * K + kt * 64 + cs * 8, &As[q * 8]);
            }
#pragma unroll
            for (int it = 0; it < 4; it++) {           // Bs: 2048 chunks
                int q = it * 512 + t;
                int r = q >> 3, c = q & 7;
                int cs = c ^ (r & 7);
                gload16(Bt + (size_t)r * K + kt * 64 + cs * 8, &Bs[q * 8]);
            }
            __syncthreads();
#pragma unroll
            for (int ks = 0; ks < 2; ks++) {
                short8 a[4], b[4];
                int cc = ks * 4 + (lane >> 4);
#pragma unroll
                for (int m = 0; m < 4; m++) {
                    int R = wm * 64 + m * 16 + (lane & 15);
                    a[m] = *(const short8*)&As[R * 64 + ((cc ^ (R & 7)) * 8)];
                }
#pragma unroll
                for (int n = 0; n < 4; n++) {
                    int R = wn * 64 + n * 16 + (lane & 15);
                    b[n] = *(const short8*)&Bs[R * 64 + ((cc ^ (R & 7)) * 8)];
                }
#pragma unroll
                for (int m = 0; m < 4; m++)
#pragma unroll
                    for (int n = 0; n < 4; n++)
                        acc[m][n] = __builtin_amdgcn_mfma_f32_16x16x32_bf16(a[m], b[n], acc[m][n], 0, 0, 0);
            }
            __syncthreads();
        }

        // epilogue: C/D layout col=lane&15, row=(lane>>4)*4+j
#pragma unroll
        for (int m = 0; m < 4; m++) {
#pragma unroll
            for (int j = 0; j < 4; j++) {
                int grow = row0 + wm * 64 + m * 16 + (lane >> 4) * 4 + j;
                if (grow >= M) continue;
                float dr = dis[list[grow]];
#pragma unroll
                for (int n = 0; n < 4; n++) {
                    int gcol = wn * 64 + n * 16 + (lane & 15);
                    float v = acc[m][n][j] + bias[gcol];
                    v = v > 0.f ? v : NEG_SLOPE * v;
                    C[(size_t)grow * 256 + gcol] = f2b(v * dr);
                }
            }
        }
    }
}

// ---------------- final: per graph, aggregate h2c at the root (via pos1), then 256x16 GEMM ----------------

__global__ __launch_bounds__(256) void final_c(const ushort* __restrict__ h2c,
                                               const float* __restrict__ dis,
                                               const int* __restrict__ rowptr,
                                               const int* __restrict__ col,
                                               const int* __restrict__ picked,
                                               const int* __restrict__ pos1,
                                               const float* __restrict__ W3,
                                               const float* __restrict__ b3,
                                               float* __restrict__ out, int G) {
    __shared__ float agg[256];
    __shared__ float red[256];
    int g = blockIdx.x;
    int t = threadIdx.x;
    if (g >= G) return;
    int i = picked[g];
    float di = dis[i];
    float a = b2f(h2c[(size_t)pos1[i] * 256 + t]);
    int e1 = rowptr[i + 1];
    for (int e = rowptr[i]; e < e1; e++) {
        a += b2f(h2c[(size_t)pos1[col[e]] * 256 + t]);
    }
    agg[t] = di * a;
    __syncthreads();
    int c = t & 15, seg = t >> 4;
    float p = 0.f;
#pragma unroll
    for (int kk = 0; kk < 16; kk++) {
        int k = seg * 16 + kk;
        p += agg[k] * W3[k * 16 + c];
    }
    red[t] = p;
    __syncthreads();
    if (t < 16) {
        float sres = 0.f;
#pragma unroll
        for (int ss = 0; ss < 16; ss++) sres += red[ss * 16 + t];
        out[g * 16 + t] = sres + b3[t];
    }
}

// ---------------- launch ----------------

extern "C" void kernel_launch(void* const* d_in, const int* in_sizes, int n_in,
                              void* d_out, int out_size, void* d_ws, size_t ws_size,
                              hipStream_t stream) {
    const float* x   = (const float*)d_in[0];
    const int* ei    = (const int*)d_in[1];
    const int* batch = (const int*)d_in[2];
    const float* W1  = (const float*)d_in[3];
    const float* b1  = (const float*)d_in[4];
    const float* W2  = (const float*)d_in[5];
    const float* b2  = (const float*)d_in[6];
    const float* W3  = (const float*)d_in[7];
    const float* b3  = (const float*)d_in[8];

    const int IN = 128, H = 256, OUT = 16;
    int N = in_sizes[0] / IN;
    int E = in_sizes[1] / 2;
    int G = out_size / OUT;
    const int* srcp = ei;
    const int* dstp = ei + E;

    char* p = (char*)d_ws;
    auto carve = [&](size_t bytes) {
        char* q = p;
        p += (bytes + 255) & ~(size_t)255;
        return q;
    };
    int*    cnt      = (int*)carve((size_t)N * 4);
    int*    flag1    = (int*)carve((size_t)N * 4);
    int*    flag2    = (int*)carve((size_t)N * 4);
    int*    rootflag = (int*)carve((size_t)N * 4);
    float*  dis    = (float*)carve((size_t)N * 4);
    int*    rowptr = (int*)carve(((size_t)N + 1) * 4);
    int*    cur    = (int*)carve((size_t)N * 4);
    int4*   tbsums = (int4*)carve(1024 * 16);
    int*    counts = (int*)carve(256);
    int*    picked = (int*)carve((size_t)G * 4);
    int*    pos1   = (int*)carve((size_t)N * 4);
    int*    pos2   = (int*)carve((size_t)N * 4);
    int*    list1  = (int*)carve((size_t)N * 4);
    int*    list2  = (int*)carve((size_t)N * 4);
    int*    col    = (int*)carve((size_t)E * 4);
    ushort* W1t    = (ushort*)carve((size_t)256 * 128 * 2);
    ushort* W2t    = (ushort*)carve((size_t)256 * 256 * 2);
    ushort* RA     = (ushort*)carve((size_t)N * H * 2);  // aggXc, then agg1c
    ushort* RB     = (ushort*)carve((size_t)N * H * 2);  // h1c, then h2c

    ushort* aggXc = RA;   // [M2][128]
    ushort* agg1c = RA;   // [M1][256] (aggXc dead after gemm1)
    ushort* h1c   = RB;   // [M2][256]
    ushort* h2c   = RB;   // [M1][256] (h1c dead after agg2)

    int nb = (N + 1023) / 1024;
    int e4 = (E + 3) / 4;
    int epN = (e4 > N ? e4 : N);
    int scanw_grid = (nb > 384 ? nb : 384);  // tscan1 + wtrans slices

    // init: zero cnt/flag1/flag2, roots, picked
    init_kernel<<<(N + 255) / 256, 256, 0, stream>>>(batch, cnt, flag1, flag2, rootflag, picked, N);

    // E-pass 1: degrees + frontier1
    count_f1<<<(e4 + 255) / 256, 256, 0, stream>>>(srcp, dstp, rootflag, cnt, flag1, E);

    // E-pass 2: frontier2
    frontier2v<<<(epN + 255) / 256, 256, 0, stream>>>(srcp, dstp, flag1, flag2, E, N);

    // fused triple scan + dis + weight transpose
    tscan1w<<<scanw_grid, 256, 0, stream>>>(cnt, flag1, flag2, tbsums, dis, N, nb, W1, W1t, W2, W2t);
    tscan2<<<1, 1024, 0, stream>>>(tbsums, counts, rowptr, N, nb);
    tscan3<<<nb, 256, 0, stream>>>(cnt, flag1, flag2, tbsums, rowptr, cur, pos1, pos2, list1, list2, N);

    // E-pass 3: filtered CSR fill
    fill_fv<<<(e4 + 255) / 256, 256, 0, stream>>>(srcp, dstp, flag2, cur, col, E);

    // layer 1 on S2: aggXc = dis*(sum dis_s*x[s] + dis_i*x[i]); h1c = dis*leaky(aggXc@W1 + b1)
    aggx_c<<<1024, 256, 0, stream>>>(x, dis, rowptr, col, list2, counts, aggXc);
    gemm_c<128><<<256, 512, 0, stream>>>(aggXc, W1t, b1, dis, list2, counts, 1, h1c);

    // layer 2 on S1: agg1c = dis*(sum h1c); h2c = dis*leaky(agg1c@W2 + b2)
    agg2_c<<<128, 256, 0, stream>>>(h1c, dis, rowptr, col, list1, pos2, counts, agg1c);
    gemm_c<256><<<64, 512, 0, stream>>>(agg1c, W2t, b2, dis, list1, counts, 0, h2c);

    // layer 3 at roots
    final_c<<<G, 256, 0, stream>>>(h2c, dis, rowptr, col, picked, pos1, W3, b3, (float*)d_out, G);
}